// Round 10
// baseline (712.699 us; speedup 1.0000x reference)
//
#include <hip/hip_runtime.h>
#include <stdint.h>

// ---------------------------------------------------------------------------
// TransformerBlock (masked-subnetwork block) for MI355X / gfx950.  Round 10:
//  - k1 rebuilt on MFMA: the 48-way masked sum is a (48x35)@(35x512) GEMM per
//    position -> matrix cores, accumulators in AGPRs by design.  Rounds 4-9
//    proved the VALU+register approach is allocator-bound (~2.5x traffic
//    floor).  A-operand = precomputed bf16 mask matrix (L2-hot); B staged
//    through a 144B-row LDS tile; epilogue repacks through LDS for 256B-burst
//    nrm stores; stats = shuffle + atomicAdd raw (S1,S2).
//  - everything else identical to round 9.
// ---------------------------------------------------------------------------

#define SEQ 2048
#define DM 1024
#define NHEADS 16
#define DH 64
#define DMLP 4096
#define PN 35
#define TOTN 51
#define OUTN 52
#define LNEPS 1e-5f
#define L2E 1.44269504088896340736f

typedef __bf16 bf16x8 __attribute__((ext_vector_type(8)));
typedef float f32x4 __attribute__((ext_vector_type(4)));
typedef unsigned short u16x8 __attribute__((ext_vector_type(8)));

static __device__ __forceinline__ unsigned short f2bf(float f) {
    unsigned int u = __builtin_bit_cast(unsigned int, f);
    u += 0x7fffu + ((u >> 16) & 1u);
    return (unsigned short)(u >> 16);
}

static __device__ __forceinline__ float gelu_tanh(float x) {
    float u = 0.7978845608028654f * x * (1.f + 0.044715f * x * x);
    float e = exp2f(u * (2.f * L2E));          // e^{2u}
    float th = 1.f - 2.f / (e + 1.f);          // tanh(u)
    return 0.5f * x * (1.f + th);
}

// async global->LDS, 16B per lane; lds dest wave-uniform base + lane*16.
static __device__ __forceinline__ void gload_lds16(const void* g, void* l) {
    __builtin_amdgcn_global_load_lds(
        (const __attribute__((address_space(1))) unsigned int*)g,
        (__attribute__((address_space(3))) unsigned int*)l, 16, 0, 0);
}

// XOR-granule swizzle: LDS[row][g] holds global[row][g ^ (row&7)], g = 16B
// granule within a 128B row.
static __device__ __forceinline__ int swz_src(int lane) {
    return ((lane & 7) ^ ((lane >> 3) & 7)) * 8;
}
static __device__ __forceinline__ int swz_off(int r, int g) {
    return ((g ^ (r & 7)) * 16);
}

// ---------------------------------------------------------------------------
// prep: rotary table, bf16 mask matrix (A-operand), biases, zero stats/colsums.
// maskAb[t*64+n] (bf16): t<48 -> mask_{q,k,v}[n, t&15]>0 (t>>4 = q/k/v);
// t==48 -> mlp mask; else / n>=35 -> 0.
// ---------------------------------------------------------------------------
__global__ void prep_all(const float* __restrict__ mq, const float* __restrict__ mk,
                         const float* __restrict__ mv, const float* __restrict__ mmlp,
                         const float* __restrict__ bQ, const float* __restrict__ bK,
                         const float* __restrict__ bV,
                         float* __restrict__ rot, unsigned short* __restrict__ maskAb,
                         float* __restrict__ mlpmaskf, float* __restrict__ biasQKV,
                         float* __restrict__ colWqkv, float* __restrict__ colWin,
                         float* __restrict__ statsQ, float* __restrict__ statsM2) {
    int bid = blockIdx.x, tid = threadIdx.x;
    if (bid < 256) {
        int id = bid * 256 + tid;            // 2048*32
        int s = id >> 5, j = id & 31;
        float freq = powf(10000.f, (float)j * (1.f / 32.f));
        float ang = (float)s / freq;
        rot[s * 64 + j] = sinf(ang);
        rot[s * 64 + 32 + j] = cosf(ang);
    } else if (bid == 256) {
        if (tid < 64) {
            int t = tid;
            for (int n = 0; n < 64; ++n) {
                float f = 0.f;
                if (n < PN) {
                    if (t < 48) {
                        int ty = t >> 4, h = t & 15;
                        const float* src = (ty == 0) ? mq : (ty == 1 ? mk : mv);
                        f = (src[n * NHEADS + h] > 0.f) ? 1.f : 0.f;
                    } else if (t == 48) {
                        f = (mmlp[n] > 0.f) ? 1.f : 0.f;
                    }
                }
                maskAb[t * 64 + n] = f2bf(f);
            }
        }
        if (tid >= 64 && tid < 112) {
            int t = tid - 64;
            int ty = t >> 4, h = t & 15;
            const float* bsrc = (ty == 0) ? bQ : (ty == 1 ? bK : bV);
            for (int d = 0; d < DH; ++d) biasQKV[t * 64 + d] = bsrc[h * DH + d];
        }
        if (tid >= 112 && tid < 176) {
            int i = tid - 112;
            mlpmaskf[i] = (i < TOTN && mmlp[i] > 0.f) ? 1.f : 0.f;
        }
    } else if (bid < 289) {                  // 32 blocks: zero statsQ (48*SEQ*2)
        for (int i = (bid - 257) * 256 + tid; i < 48 * SEQ * 2; i += 32 * 256)
            statsQ[i] = 0.f;
    } else if (bid == 289) {
        for (int i = tid; i < SEQ * 2; i += 256) statsM2[i] = 0.f;
    } else if (bid == 290) {
        for (int i = tid; i < 3072; i += 256) colWqkv[i] = 0.f;
    } else {
        for (int i = tid; i < DMLP; i += 256) colWin[i] = 0.f;
    }
}

// ---------------------------------------------------------------------------
// All weight transposes in one launch.  f32 KxN row-major -> bf16 NxK
// row-major; optional column-sum accumulation.  Flat grid of 12288 blocks.
// ---------------------------------------------------------------------------
__global__ void wtrans_all(const float* __restrict__ WQ, const float* __restrict__ WK,
                           const float* __restrict__ WV, const float* __restrict__ WO,
                           const float* __restrict__ Win, const float* __restrict__ Wout,
                           unsigned short* __restrict__ WtQKV, unsigned short* __restrict__ WtO,
                           unsigned short* __restrict__ WtIn, unsigned short* __restrict__ WtOut,
                           float* __restrict__ colWqkv, float* __restrict__ colWin) {
    int bid = blockIdx.x;
    const float* src; unsigned short* dst;
    int K, N, n0, k0;
    float* cs = nullptr;
    if (bid < 3072) {                        // W_Q / W_K / W_V: each 16 z * 64 blocks
        int ty = bid >> 10;                  // 0,1,2
        int b = bid & 1023;
        int z = b >> 6, r = b & 63;
        int zeff = ty * 16 + z;
        src = ((ty == 0) ? WQ : (ty == 1 ? WK : WV)) + (size_t)z * DM * DH;
        dst = WtQKV + (size_t)zeff * DH * DM;
        K = DM; N = DH;
        n0 = (r & 1) * 32; k0 = (r >> 1) * 32;
        cs = colWqkv + zeff * 64;
    } else if (bid < 4096) {                 // W_O: 16 z * 64 blocks
        int b = bid - 3072;
        int z = b >> 6, r = b & 63;
        src = WO + (size_t)z * DH * DM;
        dst = WtO + (size_t)z * DM * DH;
        K = DH; N = DM;
        n0 = (r & 31) * 32; k0 = (r >> 5) * 32;
    } else if (bid < 8192) {                 // W_in: 128 x 32
        int b = bid - 4096;
        src = Win; dst = WtIn;
        K = DM; N = DMLP;
        n0 = (b & 127) * 32; k0 = (b >> 7) * 32;
        cs = colWin;
    } else {                                 // W_out: 32 x 128
        int b = bid - 8192;
        src = Wout; dst = WtOut;
        K = DMLP; N = DM;
        n0 = (b & 31) * 32; k0 = (b >> 5) * 32;
    }
    __shared__ float t[32][33];
    int tx = threadIdx.x & 31, ty2 = threadIdx.x >> 5;   // 32x8
#pragma unroll
    for (int r = 0; r < 4; ++r) {
        int k = ty2 + r * 8;
        t[k][tx] = src[(size_t)(k0 + k) * N + n0 + tx];
    }
    __syncthreads();
#pragma unroll
    for (int r = 0; r < 4; ++r) {
        int n = ty2 + r * 8;
        dst[(size_t)(n0 + n) * K + k0 + tx] = f2bf(t[tx][n]);
    }
    if (cs != nullptr && ty2 == 0) {
        float s = 0.f;
#pragma unroll
        for (int k = 0; k < 32; ++k) s += t[k][tx];
        atomicAdd(&cs[n0 + tx], s);
    }
}

// ---------------------------------------------------------------------------
// K1 (MFMA): grid (SEQ, 2) x 256.  Per block: stage resid[s][0..34][c-half]
// into LDS tile T[c 512][n 64+pad] (bf16, 144B rows), copy resid -> out,
// prevpart via 1 fmac/n.  Then D[t][c] = mask[t][n] @ T[c][n]^T via
// mfma_16x16x32 (A=maskAb rows t, B=T rows c).  Epilogue: stats from f32 acc
// (shuffle + atomicAdd raw S1,S2), acc -> LDS repack -> coalesced bf16 nrm.
// ---------------------------------------------------------------------------
__launch_bounds__(256, 2)
__global__ void k1_masked_norm(const float* __restrict__ resid,
                               const unsigned short* __restrict__ maskAb,
                               const float* __restrict__ mlpmaskf,
                               float* __restrict__ outp,
                               unsigned short* __restrict__ nrm,
                               float* __restrict__ statsQ,
                               float* __restrict__ prevpart) {
    const int s = blockIdx.x, half = blockIdx.y;
    const int tid = threadIdx.x;
    const int lane = tid & 63, w = tid >> 6;
    const int cl = lane & 15, rq = lane >> 4;
    __shared__ unsigned short T[512 * 72];   // [c_local][72] shorts, 144B rows

    const int c0 = half * 512;
    const float2* rp = (const float2*)(resid + (size_t)s * PN * DM + c0) + tid;
    float2* op = (float2*)(outp + (size_t)s * OUTN * DM + c0) + tid;
    const int r0 = 2 * tid, r1 = 2 * tid + 1;

    // zero n=32..63 of this thread's two rows (16B writes, aligned)
    {
        uint4 z = make_uint4(0u, 0u, 0u, 0u);
        *(uint4*)&T[r0 * 72 + 32] = z; *(uint4*)&T[r0 * 72 + 40] = z;
        *(uint4*)&T[r0 * 72 + 48] = z; *(uint4*)&T[r0 * 72 + 56] = z;
        *(uint4*)&T[r1 * 72 + 32] = z; *(uint4*)&T[r1 * 72 + 40] = z;
        *(uint4*)&T[r1 * 72 + 48] = z; *(uint4*)&T[r1 * 72 + 56] = z;
    }

    float pmx = 0.f, pmy = 0.f;
    float2 q0 = rp[0];
    float2 q1 = rp[1 * (DM / 2)];
    float2 q2 = rp[2 * (DM / 2)];
    float2 q3 = rp[3 * (DM / 2)];
#pragma unroll 1
    for (int n = 0; n < PN; ++n) {
        float2 v = q0;
        q0 = q1; q1 = q2; q2 = q3;
        int np = (n + 4 < PN) ? (n + 4) : (PN - 1);
        q3 = rp[np * (DM / 2)];
        op[n * (DM / 2)] = v;
        float mm = mlpmaskf[n];              // uniform s_load
        pmx += mm * v.x;
        pmy += mm * v.y;
        T[r0 * 72 + n] = f2bf(v.x);
        T[r1 * 72 + n] = f2bf(v.y);
    }
    ((float2*)(prevpart + (size_t)s * DM + c0))[tid] = make_float2(pmx, pmy);
    __syncthreads();

    // A fragments: mask rows t (tiny, L2-hot)
    bf16x8 a[3][2];
#pragma unroll
    for (int mt = 0; mt < 3; ++mt)
#pragma unroll
        for (int ks = 0; ks < 2; ++ks)
            a[mt][ks] = *(const bf16x8*)(maskAb + (mt * 16 + cl) * 64 + ks * 32 + rq * 8);

    f32x4 acc[3][8];
#pragma unroll
    for (int mt = 0; mt < 3; ++mt)
#pragma unroll
        for (int nt = 0; nt < 8; ++nt) acc[mt][nt] = 0.f;

#pragma unroll
    for (int ks = 0; ks < 2; ++ks)
#pragma unroll
        for (int nt = 0; nt < 8; ++nt) {
            int row = w * 128 + nt * 16 + cl;
            bf16x8 b = *(const bf16x8*)&T[row * 72 + ks * 32 + rq * 8];
#pragma unroll
            for (int mt = 0; mt < 3; ++mt)
                acc[mt][nt] = __builtin_amdgcn_mfma_f32_16x16x32_bf16(a[mt][ks], b, acc[mt][nt], 0, 0, 0);
        }

    // stats: S1,S2 over this wave's 128 c, per t (f32 accs)
#pragma unroll
    for (int mt = 0; mt < 3; ++mt)
#pragma unroll
        for (int rr = 0; rr < 4; ++rr) {
            float s1 = 0.f, s2 = 0.f;
#pragma unroll
            for (int nt = 0; nt < 8; ++nt) {
                float v = acc[mt][nt][rr];
                s1 += v;
                s2 += v * v;
            }
            s1 += __shfl_xor(s1, 1); s2 += __shfl_xor(s2, 1);
            s1 += __shfl_xor(s1, 2); s2 += __shfl_xor(s2, 2);
            s1 += __shfl_xor(s1, 4); s2 += __shfl_xor(s2, 4);
            s1 += __shfl_xor(s1, 8); s2 += __shfl_xor(s2, 8);
            if (cl == 0) {
                int t = mt * 16 + rq * 4 + rr;
                float* st = statsQ + ((size_t)t * SEQ + s) * 2;
                atomicAdd(st, s1);
                atomicAdd(st + 1, s2);
            }
        }

    __syncthreads();   // everyone done reading T before repack overwrites

    // repack acc -> Lw[48][128] bf16, then coalesced 16B nrm stores
    unsigned short* Lw = T + w * 6144;
#pragma unroll
    for (int mt = 0; mt < 3; ++mt)
#pragma unroll
        for (int nt = 0; nt < 8; ++nt)
#pragma unroll
            for (int rr = 0; rr < 4; ++rr) {
                int t = mt * 16 + rq * 4 + rr;
                Lw[t * 128 + nt * 16 + cl] = f2bf(acc[mt][nt][rr]);
            }
#pragma unroll
    for (int i = 0; i < 12; ++i) {
        int t = i * 4 + rq;
        u16x8 vv = *(const u16x8*)&Lw[t * 128 + cl * 8];
        *(u16x8*)(nrm + ((size_t)t * SEQ + s) * DM + c0 + w * 128 + cl * 8) = vv;
    }
}

// ---------------------------------------------------------------------------
// m97-style bf16 GEMM: A MxK bf16 row-major, Bt NxK bf16 row-major.
// C = A*Bt^T.  gload_lds(16B) staging, XOR-granule swizzled LDS, BK=64.
// EPI 0: f32 out + bias*scale
// EPI 1: LN-affine (RAW S1,S2) + bias + rotary(q,k) + q*0.125 -> bf16;
//        V transposed to Vt.
// EPI 2: LN-affine (RAW S1,S2) + bias + gelu -> bf16
// ---------------------------------------------------------------------------
template <int MF, int NF, int WGM, int WGN, int EPI>
__launch_bounds__(256, 2)
__global__ void gemm2(const unsigned short* __restrict__ A, size_t aZ, int lda,
                      const unsigned short* __restrict__ Bt, size_t bZ, int ldb,
                      float* __restrict__ Cf, unsigned short* __restrict__ Cb,
                      size_t cZ, int ldc,
                      const float* __restrict__ stats, size_t statsZ,
                      const float* __restrict__ colW, size_t colwZ,
                      const float* __restrict__ bias, size_t biasZ, float biasScale,
                      const float* __restrict__ rot, unsigned short* __restrict__ Vt,
                      int K) {
    constexpr int BM = WGM * 16 * MF;
    constexpr int BN = WGN * 16 * NF;
    constexpr int nA = BM / 32;
    constexpr int nB = BN / 32;
    __shared__ unsigned short As[BM * 64];
    __shared__ unsigned short Bs[BN * 64];
    const int tid = threadIdx.x;
    const int lane = tid & 63;
    const int w = tid >> 6;
    const int wm = w % WGM, wn = w / WGM;
    const int z = blockIdx.z;
    const int m0 = blockIdx.x * BM;
    const int n0 = blockIdx.y * BN;
    const int cl = lane & 15, rq = lane >> 4;

    const unsigned short* Ab = A + (size_t)z * aZ + (size_t)m0 * lda;
    const unsigned short* Bb = Bt + (size_t)z * bZ + (size_t)n0 * ldb;
    const int lrow8 = lane >> 3;
    const int scol = swz_src(lane);

    f32x4 acc[MF][NF];
#pragma unroll
    for (int mf = 0; mf < MF; ++mf)
#pragma unroll
        for (int nf = 0; nf < NF; ++nf) acc[mf][nf] = 0.f;

    for (int k0 = 0; k0 < K; k0 += 64) {
        __syncthreads();
#pragma unroll
        for (int i = 0; i < nA; ++i) {
            int c = w * nA + i;
            int row = c * 8 + lrow8;
            gload_lds16(Ab + (size_t)row * lda + k0 + scol, (char*)As + c * 1024);
        }
#pragma unroll
        for (int i = 0; i < nB; ++i) {
            int c = w * nB + i;
            int row = c * 8 + lrow8;
            gload_lds16(Bb + (size_t)row * ldb + k0 + scol, (char*)Bs + c * 1024);
        }
        __syncthreads();
#pragma unroll
        for (int ks = 0; ks < 2; ++ks) {
            bf16x8 a[MF], b[NF];
#pragma unroll
            for (int mf = 0; mf < MF; ++mf) {
                int ra = (wm * MF + mf) * 16 + cl;
                a[mf] = *(const bf16x8*)((const char*)As + ra * 128 + swz_off(cl, ks * 4 + rq));
            }
#pragma unroll
            for (int nf = 0; nf < NF; ++nf) {
                int rb = (wn * NF + nf) * 16 + cl;
                b[nf] = *(const bf16x8*)((const char*)Bs + rb * 128 + swz_off(cl, ks * 4 + rq));
            }
#pragma unroll
            for (int mf = 0; mf < MF; ++mf)
#pragma unroll
                for (int nf = 0; nf < NF; ++nf)
                    acc[mf][nf] = __builtin_amdgcn_mfma_f32_16x16x32_bf16(a[mf], b[nf], acc[mf][nf], 0, 0, 0);
        }
    }

    if constexpr (EPI == 0) {
        float* Cz = Cf + (size_t)z * cZ;
        const float* bz = bias + (size_t)z * biasZ;
#pragma unroll
        for (int mf = 0; mf < MF; ++mf)
#pragma unroll
            for (int nf = 0; nf < NF; ++nf) {
                int col = n0 + wn * (16 * NF) + nf * 16 + cl;
                float bv = bz[col] * biasScale;
#pragma unroll
                for (int rr = 0; rr < 4; ++rr) {
                    int row = m0 + wm * (16 * MF) + mf * 16 + rq * 4 + rr;
                    Cz[(size_t)row * ldc + col] = acc[mf][nf][rr] + bv;
                }
            }
    } else if constexpr (EPI == 1) {
        const int t = z >> 4;                      // 0=q 1=k 2=v
        const int h = z & 15;
        const float qs = (t == 0) ? 0.125f : 1.f;
        float vals[MF][NF][4];
        float meanv[MF][4], invv[MF][4];
#pragma unroll
        for (int mf = 0; mf < MF; ++mf)
#pragma unroll
            for (int rr = 0; rr < 4; ++rr) {
                int row = m0 + wm * (16 * MF) + mf * 16 + rq * 4 + rr;
                const float* st = stats + ((size_t)z * statsZ + row) * 2;
                float S1 = st[0], S2 = st[1];
                float mean = S1 * (1.f / DM);
                meanv[mf][rr] = mean;
                invv[mf][rr] = rsqrtf(S2 * (1.f / DM) - mean * mean + LNEPS);
            }
#pragma unroll
        for (int nf = 0; nf < NF; ++nf) {
            int col = n0 + wn * (16 * NF) + nf * 16 + cl;
            float cw = colW[(size_t)z * colwZ + col];
            float bv = bias[(size_t)z * biasZ + col];
#pragma unroll
            for (int mf = 0; mf < MF; ++mf)
#pragma unroll
                for (int rr = 0; rr < 4; ++rr)
                    vals[mf][nf][rr] = (acc[mf][nf][rr] - meanv[mf][rr] * cw) * invv[mf][rr] + bv;
        }
        if (t < 2) {   // rotary on q,k  (WGN==1, n0==0, NF==4 -> pairs (nf, nf+2))
#pragma unroll
            for (int nf = 0; nf < NF / 2; ++nf) {
                int j = nf * 16 + cl;
#pragma unroll
                for (int mf = 0; mf < MF; ++mf)
#pragma unroll
                    for (int rr = 0; rr < 4; ++rr) {
                        int row = m0 + wm * (16 * MF) + mf * 16 + rq * 4 + rr;
                        float sn = rot[row * 64 + j];
                        float cs = rot[row * 64 + 32 + j];
                        float lo = vals[mf][nf][rr], hi = vals[mf][nf + 2][rr];
                        vals[mf][nf][rr] = lo * cs - hi * sn;
                        vals[mf][nf + 2][rr] = hi * cs + lo * sn;
                    }
            }
        }
        if (t == 2) {
#pragma unroll
            for (int mf = 0; mf < MF; ++mf)
#pragma unroll
                for (int nf = 0; nf < NF; ++nf) {
                    int col = nf * 16 + cl;   // d
                    int row0 = m0 + wm * (16 * MF) + mf * 16 + rq * 4;
                    ushort4 pk;
                    pk.x = f2bf(vals[mf][nf][0]);
                    pk.y = f2bf(vals[mf][nf][1]);
                    pk.z = f2bf(vals[mf][nf][2]);
                    pk.w = f2bf(vals[mf][nf][3]);
                    *(ushort4*)&Vt[((size_t)h * DH + col) * SEQ + row0] = pk;
                }
        } else {
            unsigned short* Cz = Cb + (size_t)z * cZ;
#pragma unroll
            for (int mf = 0; mf < MF; ++mf)
#pragma unroll
                for (int nf = 0; nf < NF; ++nf) {
                    int col = n0 + wn * (16 * NF) + nf * 16 + cl;
#pragma unroll
                    for (int rr = 0; rr < 4; ++rr) {
                        int row = m0 + wm * (16 * MF) + mf * 16 + rq * 4 + rr;
                        Cz[(size_t)row * ldc + col] = f2bf(vals[mf][nf][rr] * qs);
                    }
                }
        }
    } else {  // EPI == 2 : LN-affine from RAW (S1,S2) + bias + gelu -> bf16
        unsigned short* Cz = Cb;
#pragma unroll
        for (int mf = 0; mf < MF; ++mf)
#pragma unroll
            for (int rr = 0; rr < 4; ++rr) {
                int row = m0 + wm * (16 * MF) + mf * 16 + rq * 4 + rr;
                float S1 = stats[(size_t)row * 2];
                float S2 = stats[(size_t)row * 2 + 1];
                float mean = S1 * (1.f / DM);
                float inv = rsqrtf(S2 * (1.f / DM) - mean * mean + LNEPS);
#pragma unroll
                for (int nf = 0; nf < NF; ++nf) {
                    int col = n0 + wn * (16 * NF) + nf * 16 + cl;
                    float x = (acc[mf][nf][rr] - mean * colW[col]) * inv + bias[col];
                    Cz[(size_t)row * ldc + col] = f2bf(gelu_tanh(x));
                }
            }
    }
}

// ---------------------------------------------------------------------------
// Flash attention: balanced pairs {p, 31-p} of 64-row q-tiles, 16 heads.
// ---------------------------------------------------------------------------
__launch_bounds__(256, 2)
__global__ void flash_k(const unsigned short* __restrict__ qkv,
                        const unsigned short* __restrict__ vt,
                        unsigned short* __restrict__ zbuf) {
    const int p = blockIdx.x, h = blockIdx.y;
    const int tid = threadIdx.x, lane = tid & 63, w = tid >> 6;
    const int cl = lane & 15, rq = lane >> 4;
    const int lrow8 = lane >> 3;
    const int scol = swz_src(lane);
    const unsigned short* qb = qkv + ((size_t)h * SEQ) * DH;
    const unsigned short* kb = qkv + ((size_t)(16 + h) * SEQ) * DH;
    const unsigned short* vtb = vt + (size_t)h * DH * SEQ;

    __shared__ unsigned short Ks[64 * 64];   // [k][d] swizzled
    __shared__ unsigned short Vs[64 * 64];   // [d][k] swizzled
    __shared__ unsigned short Ps[64][72];    // padded, scalar writes

#pragma unroll 1
    for (int half = 0; half < 2; ++half) {
        const int qi = half ? (31 - p) : p;
        const int q0 = qi * 64;

        bf16x8 aq[2];
        {
            int qrow = q0 + w * 16 + cl;
            const unsigned short* qp = qb + (size_t)qrow * DH + rq * 8;
            aq[0] = *(const bf16x8*)(qp);
            aq[1] = *(const bf16x8*)(qp + 32);
        }
        float m_run[4] = {-3e38f, -3e38f, -3e38f, -3e38f};
        float l_run[4] = {0.f, 0.f, 0.f, 0.f};
        f32x4 accz[4];
#pragma unroll
        for (int nf = 0; nf < 4; ++nf) accz[nf] = 0.f;

#pragma unroll 1
        for (int j = 0; j <= qi; ++j) {
            __syncthreads();
#pragma unroll
            for (int i = 0; i < 2; ++i) {
                int c = w * 2 + i;
                int row = c * 8 + lrow8;
                gload_lds16(kb + (size_t)(j * 64 + row) * DH + scol, (char*)Ks + c * 1024);
                gload_lds16(vtb + (size_t)row * SEQ + j * 64 + scol, (char*)Vs + c * 1024);
            }
            __syncthreads();

            f32x4 sfr[4];
#pragma unroll
            for (int nf = 0; nf < 4; ++nf) sfr[nf] = 0.f;
#pragma unroll
            for (int df = 0; df < 2; ++df)
#pragma unroll
                for (int nf = 0; nf < 4; ++nf) {
                    int rb = nf * 16 + cl;
                    bf16x8 b = *(const bf16x8*)((const char*)Ks + rb * 128 + swz_off(cl, df * 4 + rq));
                    sfr[nf] = __builtin_amdgcn_mfma_f32_16x16x32_bf16(aq[df], b, sfr[nf], 0, 0, 0);
                }
            if (j == qi) {
#pragma unroll
                for (int nf = 0; nf < 4; ++nf)
#pragma unroll
                    for (int rr = 0; rr < 4; ++rr) {
                        int qg = q0 + w * 16 + rq * 4 + rr;
                        int kg = j * 64 + nf * 16 + cl;
                        if (kg > qg) sfr[nf][rr] = -1e5f;
                    }
            }
            float mnew[4], corr[4], psum[4];
#pragma unroll
            for (int rr = 0; rr < 4; ++rr) {
                float t0 = fmaxf(fmaxf(sfr[0][rr], sfr[1][rr]), fmaxf(sfr[2][rr], sfr[3][rr]));
                t0 = fmaxf(t0, __shfl_xor(t0, 1));
                t0 = fmaxf(t0, __shfl_xor(t0, 2));
                t0 = fmaxf(t0, __shfl_xor(t0, 4));
                t0 = fmaxf(t0, __shfl_xor(t0, 8));
                mnew[rr] = fmaxf(m_run[rr], t0);
                corr[rr] = exp2f((m_run[rr] - mnew[rr]) * L2E);
                psum[rr] = 0.f;
            }
#pragma unroll
            for (int nf = 0; nf < 4; ++nf)
#pragma unroll
                for (int rr = 0; rr < 4; ++rr) {
                    float pv = exp2f((sfr[nf][rr] - mnew[rr]) * L2E);
                    sfr[nf][rr] = pv;
                    psum[rr] += pv;
                }
#pragma unroll
            for (int rr = 0; rr < 4; ++rr) {
                float ps = psum[rr];
                ps += __shfl_xor(ps, 1);
                ps += __shfl_xor(ps, 2);
                ps += __shfl_xor(ps, 4);
                ps += __shfl_xor(ps, 8);
                l_run[rr] = l_run[rr] * corr[rr] + ps;
                m_run[rr] = mnew[rr];
            }
#pragma unroll
            for (int nf = 0; nf < 4; ++nf)
#pragma unroll
                for (int rr = 0; rr < 4; ++rr) accz[nf][rr] *= corr[rr];

#pragma unroll
            for (int nf = 0; nf < 4; ++nf)
#pragma unroll
                for (int rr = 0; rr < 4; ++rr)
                    Ps[w * 16 + rq * 4 + rr][nf * 16 + cl] = f2bf(sfr[nf][rr]);
#pragma unroll
            for (int ks = 0; ks < 2; ++ks) {
                bf16x8 ap = *(const bf16x8*)&Ps[w * 16 + cl][ks * 32 + rq * 8];
#pragma unroll
                for (int nf = 0; nf < 4; ++nf) {
                    int rb = nf * 16 + cl;
                    bf16x8 bv = *(const bf16x8*)((const char*)Vs + rb * 128 + swz_off(cl, ks * 4 + rq));
                    accz[nf] = __builtin_amdgcn_mfma_f32_16x16x32_bf16(ap, bv, accz[nf], 0, 0, 0);
                }
            }
        }
#pragma unroll
        for (int nf = 0; nf < 4; ++nf)
#pragma unroll
            for (int rr = 0; rr < 4; ++rr) {
                int qg = q0 + w * 16 + rq * 4 + rr;
                zbuf[((size_t)h * SEQ + qg) * DH + nf * 16 + cl] = f2bf(accz[nf][rr] / l_run[rr]);
            }
        __syncthreads();   // protect LDS before next half re-stages
    }
}

// ---------------------------------------------------------------------------
// Fused attn-out: per block (64 s-rows x 128 model cols), loop 16 heads:
// GEMM z_h @ W_O_h + b_O/16 -> out row 35+h; accumulate masked MLP residual
// (+prevpart), write midb (bf16) and atomicAdd per-row S1,S2 into statsM2.
// ---------------------------------------------------------------------------
__launch_bounds__(256, 2)
__global__ void attn_fused(const unsigned short* __restrict__ zbuf,
                           const unsigned short* __restrict__ WtO,
                           const float* __restrict__ bO,
                           const float* __restrict__ mlpmaskf,
                           const float* __restrict__ prevpart,
                           float* __restrict__ outp,
                           unsigned short* __restrict__ midb,
                           float* __restrict__ statsM2) {
    __shared__ unsigned short As[64 * 64];    // z tile [s][d]
    __shared__ unsigned short Bs[128 * 64];   // W_O^T tile [m][d]
    const int tid = threadIdx.x;
    const int lane = tid & 63;
    const int w = tid >> 6;          // WGM=1, WGN=4 -> wn = w
    const int cl = lane & 15, rq = lane >> 4;
    const int lrow8 = lane >> 3;
    const int scol = swz_src(lane);
    const int m0 = blockIdx.x * 64;
    const int n0 = blockIdx.y * 128;

    f32x4 macc[4][2];
#pragma unroll
    for (int mf = 0; mf < 4; ++mf)
#pragma unroll
        for (int nf = 0; nf < 2; ++nf)
#pragma unroll
            for (int rr = 0; rr < 4; ++rr) {
                int row = m0 + mf * 16 + rq * 4 + rr;
                int col = n0 + w * 32 + nf * 16 + cl;
                macc[mf][nf][rr] = prevpart[(size_t)row * DM + col];
            }

#pragma unroll 1
    for (int h = 0; h < NHEADS; ++h) {
        __syncthreads();
#pragma unroll
        for (int i = 0; i < 2; ++i) {
            int c = w * 2 + i;
            int row = c * 8 + lrow8;
            gload_lds16(zbuf + ((size_t)h * SEQ + m0 + row) * DH + scol, (char*)As + c * 1024);
        }
#pragma unroll
        for (int i = 0; i < 4; ++i) {
            int c = w * 4 + i;
            int row = c * 8 + lrow8;
            gload_lds16(WtO + ((size_t)h * DM + n0 + row) * DH + scol, (char*)Bs + c * 1024);
        }
        __syncthreads();
        f32x4 acc[4][2];
#pragma unroll
        for (int mf = 0; mf < 4; ++mf)
#pragma unroll
            for (int nf = 0; nf < 2; ++nf) acc[mf][nf] = 0.f;
#pragma unroll
        for (int ks = 0; ks < 2; ++ks) {
            bf16x8 a[4], b[2];
#pragma unroll
            for (int mf = 0; mf < 4; ++mf) {
                int ra = mf * 16 + cl;
                a[mf] = *(const bf16x8*)((const char*)As + ra * 128 + swz_off(cl, ks * 4 + rq));
            }
#pragma unroll
            for (int nf = 0; nf < 2; ++nf) {
                int rb = w * 32 + nf * 16 + cl;
                b[nf] = *(const bf16x8*)((const char*)Bs + rb * 128 + swz_off(cl, ks * 4 + rq));
            }
#pragma unroll
            for (int mf = 0; mf < 4; ++mf)
#pragma unroll
                for (int nf = 0; nf < 2; ++nf)
                    acc[mf][nf] = __builtin_amdgcn_mfma_f32_16x16x32_bf16(a[mf], b[nf], acc[mf][nf], 0, 0, 0);
        }
        float mh = mlpmaskf[PN + h];   // uniform
#pragma unroll
        for (int nf = 0; nf < 2; ++nf) {
            int col = n0 + w * 32 + nf * 16 + cl;
            float bv = bO[col] * (1.f / 16.f);
#pragma unroll
            for (int mf = 0; mf < 4; ++mf)
#pragma unroll
                for (int rr = 0; rr < 4; ++rr) {
                    int row = m0 + mf * 16 + rq * 4 + rr;
                    float v = acc[mf][nf][rr] + bv;
                    outp[(size_t)row * (OUTN * DM) + (PN + h) * DM + col] = v;
                    macc[mf][nf][rr] += mh * v;
                }
        }
    }
    // write midb + row-stats partials (this block covers cols n0..n0+127)
#pragma unroll
    for (int mf = 0; mf < 4; ++mf)
#pragma unroll
        for (int rr = 0; rr < 4; ++rr) {
            float v0 = macc[mf][0][rr], v1 = macc[mf][1][rr];
            int row = m0 + mf * 16 + rq * 4 + rr;
            int col0 = n0 + w * 32 + cl;
            midb[(size_t)row * DM + col0] = f2bf(v0);
            midb[(size_t)row * DM + col0 + 16] = f2bf(v1);
            float s1 = v0 + v1;
            float s2 = v0 * v0 + v1 * v1;
#pragma unroll
            for (int d = 1; d < 16; d <<= 1) {
                s1 += __shfl_xor(s1, d);
                s2 += __shfl_xor(s2, d);
            }
            if (cl == 0) {
                atomicAdd(&statsM2[row * 2], s1);
                atomicAdd(&statsM2[row * 2 + 1], s2);
            }
        }
}

// ---------------------------------------------------------------------------
extern "C" void kernel_launch(void* const* d_in, const int* in_sizes, int n_in,
                              void* d_out, int out_size, void* d_ws, size_t ws_size,
                              hipStream_t stream) {
    const float* resid = (const float*)d_in[0];
    const float* W_Q = (const float*)d_in[1];
    const float* b_Q = (const float*)d_in[2];
    const float* W_K = (const float*)d_in[3];
    const float* b_K = (const float*)d_in[4];
    const float* W_V = (const float*)d_in[5];
    const float* b_V = (const float*)d_in[6];
    const float* W_O = (const float*)d_in[7];
    const float* b_O = (const float*)d_in[8];
    const float* mql = (const float*)d_in[9];
    const float* mkl = (const float*)d_in[10];
    const float* mvl = (const float*)d_in[11];
    const float* mml = (const float*)d_in[12];
    const float* W_in = (const float*)d_in[13];
    const float* b_in = (const float*)d_in[14];
    const float* W_out = (const float*)d_in[15];
    const float* b_out = (const float*)d_in[16];
    float* out = (float*)d_out;
    (void)in_sizes; (void)n_in; (void)out_size; (void)ws_size;

    char* ws = (char*)d_ws;
    size_t off = 0;
    auto carve = [&](size_t bytes) -> void* {
        void* p = ws + off;
        off += (bytes + 255) & ~(size_t)255;
        return p;
    };
    unsigned short* nrm = (unsigned short*)carve((size_t)48 * SEQ * DM * 2);  // 192 MB
    float* statsQ = (float*)carve((size_t)48 * SEQ * 2 * 4);
    unsigned short* qkv = (unsigned short*)carve((size_t)48 * SEQ * DH * 2);  // q,k slices used
    unsigned short* vtb = (unsigned short*)carve((size_t)NHEADS * DH * SEQ * 2);
    unsigned short* zbuf = (unsigned short*)carve((size_t)NHEADS * SEQ * DH * 2);
    unsigned short* midb = (unsigned short*)carve((size_t)SEQ * DM * 2);
    float* statsM2 = (float*)carve((size_t)SEQ * 2 * 4);
    unsigned short* act = (unsigned short*)carve((size_t)SEQ * DMLP * 2);
    float* rot = (float*)carve((size_t)SEQ * 64 * 4);
    float* colWqkv = (float*)carve((size_t)48 * 64 * 4);
    float* colWin = (float*)carve((size_t)DMLP * 4);
    float* mlpmaskf = (float*)carve((size_t)64 * 4);
    float* biasQKV = (float*)carve((size_t)48 * 64 * 4);
    unsigned short* maskAb = (unsigned short*)carve((size_t)64 * 64 * 2);
    float* prevpart = (float*)carve((size_t)SEQ * DM * 4);                    // 8 MB
    unsigned short* WtQKV = (unsigned short*)carve((size_t)48 * DH * DM * 2); // 6 MB
    unsigned short* WtO = (unsigned short*)carve((size_t)16 * DM * DH * 2);   // 2 MB
    unsigned short* WtIn = (unsigned short*)carve((size_t)DMLP * DM * 2);     // 8 MB
    unsigned short* WtOut = (unsigned short*)carve((size_t)DM * DMLP * 2);    // 8 MB

    prep_all<<<292, 256, 0, stream>>>(mql, mkl, mvl, mml, b_Q, b_K, b_V,
                                      rot, maskAb, mlpmaskf, biasQKV,
                                      colWqkv, colWin, statsQ, statsM2);

    wtrans_all<<<12288, 256, 0, stream>>>(W_Q, W_K, W_V, W_O, W_in, W_out,
                                          WtQKV, WtO, WtIn, WtOut, colWqkv, colWin);

    k1_masked_norm<<<dim3(SEQ, 2), 256, 0, stream>>>(resid, maskAb, mlpmaskf, out,
                                                     nrm, statsQ, prevpart);

    // QKV projection: 48 GEMMs (2048x1024x64); V written transposed to vtb
    gemm2<2, 4, 4, 1, 1><<<dim3(16, 1, 48), 256, 0, stream>>>(
        nrm, (size_t)SEQ * DM, DM,
        WtQKV, (size_t)DH * DM, DM,
        nullptr, qkv, (size_t)SEQ * DH, DH,
        statsQ, SEQ,
        colWqkv, 64,
        biasQKV, 64, 1.f,
        rot, vtb, DM);

    flash_k<<<dim3(16, 16), 256, 0, stream>>>(qkv, vtb, zbuf);

    attn_fused<<<dim3(32, 8), 256, 0, stream>>>(zbuf, WtO, b_O, mlpmaskf, prevpart,
                                                out, midb, statsM2);

    // MLP1: (2048x1024)@(1024x4096), LN fold (raw stats) + b_in + gelu -> act
    gemm2<4, 4, 2, 2, 2><<<dim3(16, 32, 1), 256, 0, stream>>>(
        midb, 0, DM,
        WtIn, 0, DM,
        nullptr, act, 0, DMLP,
        statsM2, 0,
        colWin, 0,
        b_in, 0, 1.f,
        nullptr, nullptr, DM);

    // MLP2: (2048x4096)@(4096x1024) + b_out -> d_out row 51
    gemm2<2, 4, 2, 2, 0><<<dim3(32, 8, 1), 256, 0, stream>>>(
        act, 0, DMLP,
        WtOut, 0, DMLP,
        out + 51 * DM, nullptr, 0, OUTN * DM,
        nullptr, 0, nullptr, 0,
        b_out, 0, 1.f,
        nullptr, nullptr, DMLP);
}

// Round 11
// 684.717 us; speedup vs baseline: 1.0409x; 1.0409x over previous
//
#include <hip/hip_runtime.h>
#include <stdint.h>

// ---------------------------------------------------------------------------
// TransformerBlock (masked-subnetwork block) for MI355X / gfx950.  Round 11:
//  - k1: back to round 8's SGPR-mask/v_fmac structure, but each of the 48
//    accumulators is PINNED to an arch VGPR via inline-asm v_fmac_f32 with
//    "+v" constraint (rounds 6-10 proved the allocator otherwise parks the
//    accumulator set in AGPRs: VGPR_Count 36..64, 3x VALU ops per update).
//    One f32 column/thread, grid (SEQ,4), s_load_dwordx16 mask rows,
//    depth-2 prefetch.  MFMA k1 (round 10: 2.1e7 bank conflicts) reverted.
//  - everything else identical to rounds 8-10.
// ---------------------------------------------------------------------------

#define SEQ 2048
#define DM 1024
#define NHEADS 16
#define DH 64
#define DMLP 4096
#define PN 35
#define TOTN 51
#define OUTN 52
#define LNEPS 1e-5f
#define L2E 1.44269504088896340736f

typedef __bf16 bf16x8 __attribute__((ext_vector_type(8)));
typedef float f32x4 __attribute__((ext_vector_type(4)));
typedef float f32x16 __attribute__((ext_vector_type(16)));
typedef unsigned short u16x8 __attribute__((ext_vector_type(8)));

static __device__ __forceinline__ unsigned short f2bf(float f) {
    unsigned int u = __builtin_bit_cast(unsigned int, f);
    u += 0x7fffu + ((u >> 16) & 1u);
    return (unsigned short)(u >> 16);
}

static __device__ __forceinline__ float gelu_tanh(float x) {
    float u = 0.7978845608028654f * x * (1.f + 0.044715f * x * x);
    float e = exp2f(u * (2.f * L2E));          // e^{2u}
    float th = 1.f - 2.f / (e + 1.f);          // tanh(u)
    return 0.5f * x * (1.f + th);
}

// async global->LDS, 16B per lane; lds dest wave-uniform base + lane*16.
static __device__ __forceinline__ void gload_lds16(const void* g, void* l) {
    __builtin_amdgcn_global_load_lds(
        (const __attribute__((address_space(1))) unsigned int*)g,
        (__attribute__((address_space(3))) unsigned int*)l, 16, 0, 0);
}

// XOR-granule swizzle: LDS[row][g] holds global[row][g ^ (row&7)], g = 16B
// granule within a 128B row.
static __device__ __forceinline__ int swz_src(int lane) {
    return ((lane & 7) ^ ((lane >> 3) & 7)) * 8;
}
static __device__ __forceinline__ int swz_off(int r, int g) {
    return ((g ^ (r & 7)) * 16);
}

// ---------------------------------------------------------------------------
// prep: rotary table, mask FLOAT table, biases, zero statsQ/statsM2/colsums.
// maskf[n*64+t]: t<48 -> mask_{q,k,v}[n, t&15]>0 ? 1 : 0 (t>>4 = q/k/v);
// t==48 -> mlp mask; t>48 -> 0.
// ---------------------------------------------------------------------------
__global__ void prep_all(const float* __restrict__ mq, const float* __restrict__ mk,
                         const float* __restrict__ mv, const float* __restrict__ mmlp,
                         const float* __restrict__ bQ, const float* __restrict__ bK,
                         const float* __restrict__ bV,
                         float* __restrict__ rot, float* __restrict__ maskf,
                         float* __restrict__ mlpmaskf, float* __restrict__ biasQKV,
                         float* __restrict__ colWqkv, float* __restrict__ colWin,
                         float* __restrict__ statsQ, float* __restrict__ statsM2) {
    int bid = blockIdx.x, tid = threadIdx.x;
    if (bid < 256) {
        int id = bid * 256 + tid;            // 2048*32
        int s = id >> 5, j = id & 31;
        float freq = powf(10000.f, (float)j * (1.f / 32.f));
        float ang = (float)s / freq;
        rot[s * 64 + j] = sinf(ang);
        rot[s * 64 + 32 + j] = cosf(ang);
    } else if (bid == 256) {
        if (tid < PN) {
            int n = tid;
            for (int t = 0; t < 64; ++t) {
                float f = 0.f;
                if (t < 48) {
                    int ty = t >> 4, h = t & 15;
                    const float* src = (ty == 0) ? mq : (ty == 1 ? mk : mv);
                    f = (src[n * NHEADS + h] > 0.f) ? 1.f : 0.f;
                } else if (t == 48) {
                    f = (mmlp[n] > 0.f) ? 1.f : 0.f;
                }
                maskf[n * 64 + t] = f;
            }
        }
        if (tid >= 64 && tid < 112) {
            int t = tid - 64;
            int ty = t >> 4, h = t & 15;
            const float* bsrc = (ty == 0) ? bQ : (ty == 1 ? bK : bV);
            for (int d = 0; d < DH; ++d) biasQKV[t * 64 + d] = bsrc[h * DH + d];
        }
        if (tid >= 112 && tid < 176) {
            int i = tid - 112;
            mlpmaskf[i] = (i < TOTN && mmlp[i] > 0.f) ? 1.f : 0.f;
        }
    } else if (bid < 289) {                  // 32 blocks: zero statsQ (48*SEQ*2)
        for (int i = (bid - 257) * 256 + tid; i < 48 * SEQ * 2; i += 32 * 256)
            statsQ[i] = 0.f;
    } else if (bid == 289) {
        for (int i = tid; i < SEQ * 2; i += 256) statsM2[i] = 0.f;
    } else if (bid == 290) {
        for (int i = tid; i < 3072; i += 256) colWqkv[i] = 0.f;
    } else {
        for (int i = tid; i < DMLP; i += 256) colWin[i] = 0.f;
    }
}

// ---------------------------------------------------------------------------
// All weight transposes in one launch.  f32 KxN row-major -> bf16 NxK
// row-major; optional column-sum accumulation.  Flat grid of 12288 blocks.
// ---------------------------------------------------------------------------
__global__ void wtrans_all(const float* __restrict__ WQ, const float* __restrict__ WK,
                           const float* __restrict__ WV, const float* __restrict__ WO,
                           const float* __restrict__ Win, const float* __restrict__ Wout,
                           unsigned short* __restrict__ WtQKV, unsigned short* __restrict__ WtO,
                           unsigned short* __restrict__ WtIn, unsigned short* __restrict__ WtOut,
                           float* __restrict__ colWqkv, float* __restrict__ colWin) {
    int bid = blockIdx.x;
    const float* src; unsigned short* dst;
    int K, N, n0, k0;
    float* cs = nullptr;
    if (bid < 3072) {                        // W_Q / W_K / W_V: each 16 z * 64 blocks
        int ty = bid >> 10;                  // 0,1,2
        int b = bid & 1023;
        int z = b >> 6, r = b & 63;
        int zeff = ty * 16 + z;
        src = ((ty == 0) ? WQ : (ty == 1 ? WK : WV)) + (size_t)z * DM * DH;
        dst = WtQKV + (size_t)zeff * DH * DM;
        K = DM; N = DH;
        n0 = (r & 1) * 32; k0 = (r >> 1) * 32;
        cs = colWqkv + zeff * 64;
    } else if (bid < 4096) {                 // W_O: 16 z * 64 blocks
        int b = bid - 3072;
        int z = b >> 6, r = b & 63;
        src = WO + (size_t)z * DH * DM;
        dst = WtO + (size_t)z * DM * DH;
        K = DH; N = DM;
        n0 = (r & 31) * 32; k0 = (r >> 5) * 32;
    } else if (bid < 8192) {                 // W_in: 128 x 32
        int b = bid - 4096;
        src = Win; dst = WtIn;
        K = DM; N = DMLP;
        n0 = (b & 127) * 32; k0 = (b >> 7) * 32;
        cs = colWin;
    } else {                                 // W_out: 32 x 128
        int b = bid - 8192;
        src = Wout; dst = WtOut;
        K = DMLP; N = DM;
        n0 = (b & 31) * 32; k0 = (b >> 5) * 32;
    }
    __shared__ float t[32][33];
    int tx = threadIdx.x & 31, ty2 = threadIdx.x >> 5;   // 32x8
#pragma unroll
    for (int r = 0; r < 4; ++r) {
        int k = ty2 + r * 8;
        t[k][tx] = src[(size_t)(k0 + k) * N + n0 + tx];
    }
    __syncthreads();
#pragma unroll
    for (int r = 0; r < 4; ++r) {
        int n = ty2 + r * 8;
        dst[(size_t)(n0 + n) * K + k0 + tx] = f2bf(t[tx][n]);
    }
    if (cs != nullptr && ty2 == 0) {
        float s = 0.f;
#pragma unroll
        for (int k = 0; k < 32; ++k) s += t[k][tx];
        atomicAdd(&cs[n0 + tx], s);
    }
}

// ---------------------------------------------------------------------------
// K1: one f32 column per thread, grid (SEQ, 4) x 256.  Mask row -> SGPRs via
// s_load_dwordx16; 48 accumulators PINNED to arch VGPRs via inline-asm
// v_fmac_f32 "+v"; depth-2 value prefetch.  Emits bf16 sums, prevpart,
// atomicAdd (S1,S2) raw stats partials.
// ---------------------------------------------------------------------------
__launch_bounds__(256, 4)
__global__ void k1_masked_norm(const float* __restrict__ resid,
                               const float* __restrict__ maskf,
                               float* __restrict__ outp,
                               unsigned short* __restrict__ nrm,
                               float* __restrict__ statsQ,
                               float* __restrict__ prevpart) {
    const int s = blockIdx.x;
    const int tid = threadIdx.x;
    const int col = blockIdx.y * 256 + tid;
    const int lane = tid & 63, w = tid >> 6;
    const float* rp = resid + (size_t)s * PN * DM + col;
    float* op = outp + (size_t)s * OUTN * DM + col;
    float A0 = 0.f, A1 = 0.f, A2 = 0.f, A3 = 0.f, A4 = 0.f, A5 = 0.f, A6 = 0.f, A7 = 0.f,
          A8 = 0.f, A9 = 0.f, A10 = 0.f, A11 = 0.f, A12 = 0.f, A13 = 0.f, A14 = 0.f, A15 = 0.f,
          A16 = 0.f, A17 = 0.f, A18 = 0.f, A19 = 0.f, A20 = 0.f, A21 = 0.f, A22 = 0.f, A23 = 0.f,
          A24 = 0.f, A25 = 0.f, A26 = 0.f, A27 = 0.f, A28 = 0.f, A29 = 0.f, A30 = 0.f, A31 = 0.f,
          A32 = 0.f, A33 = 0.f, A34 = 0.f, A35 = 0.f, A36 = 0.f, A37 = 0.f, A38 = 0.f, A39 = 0.f,
          A40 = 0.f, A41 = 0.f, A42 = 0.f, A43 = 0.f, A44 = 0.f, A45 = 0.f, A46 = 0.f, A47 = 0.f;
    float PM = 0.f;
    float v0 = rp[0];
    float v1 = rp[DM];
#pragma unroll 1
    for (int n = 0; n < PN; ++n) {
        f32x16 m0, m1, m2;
        float mml;
        asm volatile(
            "s_load_dwordx16 %0, %4, 0x0\n"
            "s_load_dwordx16 %1, %4, 0x40\n"
            "s_load_dwordx16 %2, %4, 0x80\n"
            "s_load_dword    %3, %4, 0xc0\n"
            "s_waitcnt lgkmcnt(0)\n"
            : "=s"(m0), "=s"(m1), "=s"(m2), "=s"(mml)
            : "s"(maskf + n * 64));
        int np = (n + 2 < PN) ? (n + 2) : (PN - 1);
        float v2 = rp[np * DM];
        op[n * DM] = v0;
        float vx = v0;
#define FM(A_, M_) asm("v_fmac_f32 %0, %1, %2" : "+v"(A_) : "s"(M_), "v"(vx));
        FM(A0, m0[0])   FM(A1, m0[1])   FM(A2, m0[2])   FM(A3, m0[3])
        FM(A4, m0[4])   FM(A5, m0[5])   FM(A6, m0[6])   FM(A7, m0[7])
        FM(A8, m0[8])   FM(A9, m0[9])   FM(A10, m0[10]) FM(A11, m0[11])
        FM(A12, m0[12]) FM(A13, m0[13]) FM(A14, m0[14]) FM(A15, m0[15])
        FM(A16, m1[0])  FM(A17, m1[1])  FM(A18, m1[2])  FM(A19, m1[3])
        FM(A20, m1[4])  FM(A21, m1[5])  FM(A22, m1[6])  FM(A23, m1[7])
        FM(A24, m1[8])  FM(A25, m1[9])  FM(A26, m1[10]) FM(A27, m1[11])
        FM(A28, m1[12]) FM(A29, m1[13]) FM(A30, m1[14]) FM(A31, m1[15])
        FM(A32, m2[0])  FM(A33, m2[1])  FM(A34, m2[2])  FM(A35, m2[3])
        FM(A36, m2[4])  FM(A37, m2[5])  FM(A38, m2[6])  FM(A39, m2[7])
        FM(A40, m2[8])  FM(A41, m2[9])  FM(A42, m2[10]) FM(A43, m2[11])
        FM(A44, m2[12]) FM(A45, m2[13]) FM(A46, m2[14]) FM(A47, m2[15])
        FM(PM, mml)
#undef FM
        v0 = v1;
        v1 = v2;
    }
    prevpart[(size_t)s * DM + col] = PM;
    __shared__ float wpart[4][48][2];
#define F1(A_, T) { \
    float x_ = A_; \
    nrm[((size_t)(T) * SEQ + s) * DM + col] = f2bf(x_); \
    float p1 = x_, p2 = x_ * x_; \
    p1 += __shfl_xor(p1, 1);  p2 += __shfl_xor(p2, 1); \
    p1 += __shfl_xor(p1, 2);  p2 += __shfl_xor(p2, 2); \
    p1 += __shfl_xor(p1, 4);  p2 += __shfl_xor(p2, 4); \
    p1 += __shfl_xor(p1, 8);  p2 += __shfl_xor(p2, 8); \
    p1 += __shfl_xor(p1, 16); p2 += __shfl_xor(p2, 16); \
    p1 += __shfl_xor(p1, 32); p2 += __shfl_xor(p2, 32); \
    if (lane == 0) { wpart[w][T][0] = p1; wpart[w][T][1] = p2; } }
    F1(A0, 0)   F1(A1, 1)   F1(A2, 2)   F1(A3, 3)
    F1(A4, 4)   F1(A5, 5)   F1(A6, 6)   F1(A7, 7)
    F1(A8, 8)   F1(A9, 9)   F1(A10, 10) F1(A11, 11)
    F1(A12, 12) F1(A13, 13) F1(A14, 14) F1(A15, 15)
    F1(A16, 16) F1(A17, 17) F1(A18, 18) F1(A19, 19)
    F1(A20, 20) F1(A21, 21) F1(A22, 22) F1(A23, 23)
    F1(A24, 24) F1(A25, 25) F1(A26, 26) F1(A27, 27)
    F1(A28, 28) F1(A29, 29) F1(A30, 30) F1(A31, 31)
    F1(A32, 32) F1(A33, 33) F1(A34, 34) F1(A35, 35)
    F1(A36, 36) F1(A37, 37) F1(A38, 38) F1(A39, 39)
    F1(A40, 40) F1(A41, 41) F1(A42, 42) F1(A43, 43)
    F1(A44, 44) F1(A45, 45) F1(A46, 46) F1(A47, 47)
#undef F1
    __syncthreads();
    if (tid < 96) {
        int t = tid >> 1, j = tid & 1;
        float S = wpart[0][t][j] + wpart[1][t][j] + wpart[2][t][j] + wpart[3][t][j];
        atomicAdd(&statsQ[((size_t)t * SEQ + s) * 2 + j], S);
    }
}

// ---------------------------------------------------------------------------
// m97-style bf16 GEMM: A MxK bf16 row-major, Bt NxK bf16 row-major.
// C = A*Bt^T.  gload_lds(16B) staging, XOR-granule swizzled LDS, BK=64.
// EPI 0: f32 out + bias*scale
// EPI 1: LN-affine (RAW S1,S2) + bias + rotary(q,k) + q*0.125 -> bf16;
//        V transposed to Vt.
// EPI 2: LN-affine (RAW S1,S2) + bias + gelu -> bf16
// ---------------------------------------------------------------------------
template <int MF, int NF, int WGM, int WGN, int EPI>
__launch_bounds__(256, 2)
__global__ void gemm2(const unsigned short* __restrict__ A, size_t aZ, int lda,
                      const unsigned short* __restrict__ Bt, size_t bZ, int ldb,
                      float* __restrict__ Cf, unsigned short* __restrict__ Cb,
                      size_t cZ, int ldc,
                      const float* __restrict__ stats, size_t statsZ,
                      const float* __restrict__ colW, size_t colwZ,
                      const float* __restrict__ bias, size_t biasZ, float biasScale,
                      const float* __restrict__ rot, unsigned short* __restrict__ Vt,
                      int K) {
    constexpr int BM = WGM * 16 * MF;
    constexpr int BN = WGN * 16 * NF;
    constexpr int nA = BM / 32;
    constexpr int nB = BN / 32;
    __shared__ unsigned short As[BM * 64];
    __shared__ unsigned short Bs[BN * 64];
    const int tid = threadIdx.x;
    const int lane = tid & 63;
    const int w = tid >> 6;
    const int wm = w % WGM, wn = w / WGM;
    const int z = blockIdx.z;
    const int m0 = blockIdx.x * BM;
    const int n0 = blockIdx.y * BN;
    const int cl = lane & 15, rq = lane >> 4;

    const unsigned short* Ab = A + (size_t)z * aZ + (size_t)m0 * lda;
    const unsigned short* Bb = Bt + (size_t)z * bZ + (size_t)n0 * ldb;
    const int lrow8 = lane >> 3;
    const int scol = swz_src(lane);

    f32x4 acc[MF][NF];
#pragma unroll
    for (int mf = 0; mf < MF; ++mf)
#pragma unroll
        for (int nf = 0; nf < NF; ++nf) acc[mf][nf] = 0.f;

    for (int k0 = 0; k0 < K; k0 += 64) {
        __syncthreads();
#pragma unroll
        for (int i = 0; i < nA; ++i) {
            int c = w * nA + i;
            int row = c * 8 + lrow8;
            gload_lds16(Ab + (size_t)row * lda + k0 + scol, (char*)As + c * 1024);
        }
#pragma unroll
        for (int i = 0; i < nB; ++i) {
            int c = w * nB + i;
            int row = c * 8 + lrow8;
            gload_lds16(Bb + (size_t)row * ldb + k0 + scol, (char*)Bs + c * 1024);
        }
        __syncthreads();
#pragma unroll
        for (int ks = 0; ks < 2; ++ks) {
            bf16x8 a[MF], b[NF];
#pragma unroll
            for (int mf = 0; mf < MF; ++mf) {
                int ra = (wm * MF + mf) * 16 + cl;
                a[mf] = *(const bf16x8*)((const char*)As + ra * 128 + swz_off(cl, ks * 4 + rq));
            }
#pragma unroll
            for (int nf = 0; nf < NF; ++nf) {
                int rb = (wn * NF + nf) * 16 + cl;
                b[nf] = *(const bf16x8*)((const char*)Bs + rb * 128 + swz_off(cl, ks * 4 + rq));
            }
#pragma unroll
            for (int mf = 0; mf < MF; ++mf)
#pragma unroll
                for (int nf = 0; nf < NF; ++nf)
                    acc[mf][nf] = __builtin_amdgcn_mfma_f32_16x16x32_bf16(a[mf], b[nf], acc[mf][nf], 0, 0, 0);
        }
    }

    if constexpr (EPI == 0) {
        float* Cz = Cf + (size_t)z * cZ;
        const float* bz = bias + (size_t)z * biasZ;
#pragma unroll
        for (int mf = 0; mf < MF; ++mf)
#pragma unroll
            for (int nf = 0; nf < NF; ++nf) {
                int col = n0 + wn * (16 * NF) + nf * 16 + cl;
                float bv = bz[col] * biasScale;
#pragma unroll
                for (int rr = 0; rr < 4; ++rr) {
                    int row = m0 + wm * (16 * MF) + mf * 16 + rq * 4 + rr;
                    Cz[(size_t)row * ldc + col] = acc[mf][nf][rr] + bv;
                }
            }
    } else if constexpr (EPI == 1) {
        const int t = z >> 4;                      // 0=q 1=k 2=v
        const int h = z & 15;
        const float qs = (t == 0) ? 0.125f : 1.f;
        float vals[MF][NF][4];
        float meanv[MF][4], invv[MF][4];
#pragma unroll
        for (int mf = 0; mf < MF; ++mf)
#pragma unroll
            for (int rr = 0; rr < 4; ++rr) {
                int row = m0 + wm * (16 * MF) + mf * 16 + rq * 4 + rr;
                const float* st = stats + ((size_t)z * statsZ + row) * 2;
                float S1 = st[0], S2 = st[1];
                float mean = S1 * (1.f / DM);
                meanv[mf][rr] = mean;
                invv[mf][rr] = rsqrtf(S2 * (1.f / DM) - mean * mean + LNEPS);
            }
#pragma unroll
        for (int nf = 0; nf < NF; ++nf) {
            int col = n0 + wn * (16 * NF) + nf * 16 + cl;
            float cw = colW[(size_t)z * colwZ + col];
            float bv = bias[(size_t)z * biasZ + col];
#pragma unroll
            for (int mf = 0; mf < MF; ++mf)
#pragma unroll
                for (int rr = 0; rr < 4; ++rr)
                    vals[mf][nf][rr] = (acc[mf][nf][rr] - meanv[mf][rr] * cw) * invv[mf][rr] + bv;
        }
        if (t < 2) {   // rotary on q,k  (WGN==1, n0==0, NF==4 -> pairs (nf, nf+2))
#pragma unroll
            for (int nf = 0; nf < NF / 2; ++nf) {
                int j = nf * 16 + cl;
#pragma unroll
                for (int mf = 0; mf < MF; ++mf)
#pragma unroll
                    for (int rr = 0; rr < 4; ++rr) {
                        int row = m0 + wm * (16 * MF) + mf * 16 + rq * 4 + rr;
                        float sn = rot[row * 64 + j];
                        float cs = rot[row * 64 + 32 + j];
                        float lo = vals[mf][nf][rr], hi = vals[mf][nf + 2][rr];
                        vals[mf][nf][rr] = lo * cs - hi * sn;
                        vals[mf][nf + 2][rr] = hi * cs + lo * sn;
                    }
            }
        }
        if (t == 2) {
#pragma unroll
            for (int mf = 0; mf < MF; ++mf)
#pragma unroll
                for (int nf = 0; nf < NF; ++nf) {
                    int col = nf * 16 + cl;   // d
                    int row0 = m0 + wm * (16 * MF) + mf * 16 + rq * 4;
                    ushort4 pk;
                    pk.x = f2bf(vals[mf][nf][0]);
                    pk.y = f2bf(vals[mf][nf][1]);
                    pk.z = f2bf(vals[mf][nf][2]);
                    pk.w = f2bf(vals[mf][nf][3]);
                    *(ushort4*)&Vt[((size_t)h * DH + col) * SEQ + row0] = pk;
                }
        } else {
            unsigned short* Cz = Cb + (size_t)z * cZ;
#pragma unroll
            for (int mf = 0; mf < MF; ++mf)
#pragma unroll
                for (int nf = 0; nf < NF; ++nf) {
                    int col = n0 + wn * (16 * NF) + nf * 16 + cl;
#pragma unroll
                    for (int rr = 0; rr < 4; ++rr) {
                        int row = m0 + wm * (16 * MF) + mf * 16 + rq * 4 + rr;
                        Cz[(size_t)row * ldc + col] = f2bf(vals[mf][nf][rr] * qs);
                    }
                }
        }
    } else {  // EPI == 2 : LN-affine from RAW (S1,S2) + bias + gelu -> bf16
        unsigned short* Cz = Cb;
#pragma unroll
        for (int mf = 0; mf < MF; ++mf)
#pragma unroll
            for (int rr = 0; rr < 4; ++rr) {
                int row = m0 + wm * (16 * MF) + mf * 16 + rq * 4 + rr;
                float S1 = stats[(size_t)row * 2];
                float S2 = stats[(size_t)row * 2 + 1];
                float mean = S1 * (1.f / DM);
                float inv = rsqrtf(S2 * (1.f / DM) - mean * mean + LNEPS);
#pragma unroll
                for (int nf = 0; nf < NF; ++nf) {
                    int col = n0 + wn * (16 * NF) + nf * 16 + cl;
                    float x = (acc[mf][nf][rr] - mean * colW[col]) * inv + bias[col];
                    Cz[(size_t)row * ldc + col] = f2bf(gelu_tanh(x));
                }
            }
    }
}

// ---------------------------------------------------------------------------
// Flash attention: balanced pairs {p, 31-p} of 64-row q-tiles, 16 heads.
// ---------------------------------------------------------------------------
__launch_bounds__(256, 2)
__global__ void flash_k(const unsigned short* __restrict__ qkv,
                        const unsigned short* __restrict__ vt,
                        unsigned short* __restrict__ zbuf) {
    const int p = blockIdx.x, h = blockIdx.y;
    const int tid = threadIdx.x, lane = tid & 63, w = tid >> 6;
    const int cl = lane & 15, rq = lane >> 4;
    const int lrow8 = lane >> 3;
    const int scol = swz_src(lane);
    const unsigned short* qb = qkv + ((size_t)h * SEQ) * DH;
    const unsigned short* kb = qkv + ((size_t)(16 + h) * SEQ) * DH;
    const unsigned short* vtb = vt + (size_t)h * DH * SEQ;

    __shared__ unsigned short Ks[64 * 64];   // [k][d] swizzled
    __shared__ unsigned short Vs[64 * 64];   // [d][k] swizzled
    __shared__ unsigned short Ps[64][72];    // padded, scalar writes

#pragma unroll 1
    for (int half = 0; half < 2; ++half) {
        const int qi = half ? (31 - p) : p;
        const int q0 = qi * 64;

        bf16x8 aq[2];
        {
            int qrow = q0 + w * 16 + cl;
            const unsigned short* qp = qb + (size_t)qrow * DH + rq * 8;
            aq[0] = *(const bf16x8*)(qp);
            aq[1] = *(const bf16x8*)(qp + 32);
        }
        float m_run[4] = {-3e38f, -3e38f, -3e38f, -3e38f};
        float l_run[4] = {0.f, 0.f, 0.f, 0.f};
        f32x4 accz[4];
#pragma unroll
        for (int nf = 0; nf < 4; ++nf) accz[nf] = 0.f;

#pragma unroll 1
        for (int j = 0; j <= qi; ++j) {
            __syncthreads();
#pragma unroll
            for (int i = 0; i < 2; ++i) {
                int c = w * 2 + i;
                int row = c * 8 + lrow8;
                gload_lds16(kb + (size_t)(j * 64 + row) * DH + scol, (char*)Ks + c * 1024);
                gload_lds16(vtb + (size_t)row * SEQ + j * 64 + scol, (char*)Vs + c * 1024);
            }
            __syncthreads();

            f32x4 sfr[4];
#pragma unroll
            for (int nf = 0; nf < 4; ++nf) sfr[nf] = 0.f;
#pragma unroll
            for (int df = 0; df < 2; ++df)
#pragma unroll
                for (int nf = 0; nf < 4; ++nf) {
                    int rb = nf * 16 + cl;
                    bf16x8 b = *(const bf16x8*)((const char*)Ks + rb * 128 + swz_off(cl, df * 4 + rq));
                    sfr[nf] = __builtin_amdgcn_mfma_f32_16x16x32_bf16(aq[df], b, sfr[nf], 0, 0, 0);
                }
            if (j == qi) {
#pragma unroll
                for (int nf = 0; nf < 4; ++nf)
#pragma unroll
                    for (int rr = 0; rr < 4; ++rr) {
                        int qg = q0 + w * 16 + rq * 4 + rr;
                        int kg = j * 64 + nf * 16 + cl;
                        if (kg > qg) sfr[nf][rr] = -1e5f;
                    }
            }
            float mnew[4], corr[4], psum[4];
#pragma unroll
            for (int rr = 0; rr < 4; ++rr) {
                float t0 = fmaxf(fmaxf(sfr[0][rr], sfr[1][rr]), fmaxf(sfr[2][rr], sfr[3][rr]));
                t0 = fmaxf(t0, __shfl_xor(t0, 1));
                t0 = fmaxf(t0, __shfl_xor(t0, 2));
                t0 = fmaxf(t0, __shfl_xor(t0, 4));
                t0 = fmaxf(t0, __shfl_xor(t0, 8));
                mnew[rr] = fmaxf(m_run[rr], t0);
                corr[rr] = exp2f((m_run[rr] - mnew[rr]) * L2E);
                psum[rr] = 0.f;
            }
#pragma unroll
            for (int nf = 0; nf < 4; ++nf)
#pragma unroll
                for (int rr = 0; rr < 4; ++rr) {
                    float pv = exp2f((sfr[nf][rr] - mnew[rr]) * L2E);
                    sfr[nf][rr] = pv;
                    psum[rr] += pv;
                }
#pragma unroll
            for (int rr = 0; rr < 4; ++rr) {
                float ps = psum[rr];
                ps += __shfl_xor(ps, 1);
                ps += __shfl_xor(ps, 2);
                ps += __shfl_xor(ps, 4);
                ps += __shfl_xor(ps, 8);
                l_run[rr] = l_run[rr] * corr[rr] + ps;
                m_run[rr] = mnew[rr];
            }
#pragma unroll
            for (int nf = 0; nf < 4; ++nf)
#pragma unroll
                for (int rr = 0; rr < 4; ++rr) accz[nf][rr] *= corr[rr];

#pragma unroll
            for (int nf = 0; nf < 4; ++nf)
#pragma unroll
                for (int rr = 0; rr < 4; ++rr)
                    Ps[w * 16 + rq * 4 + rr][nf * 16 + cl] = f2bf(sfr[nf][rr]);
#pragma unroll
            for (int ks = 0; ks < 2; ++ks) {
                bf16x8 ap = *(const bf16x8*)&Ps[w * 16 + cl][ks * 32 + rq * 8];
#pragma unroll
                for (int nf = 0; nf < 4; ++nf) {
                    int rb = nf * 16 + cl;
                    bf16x8 bv = *(const bf16x8*)((const char*)Vs + rb * 128 + swz_off(cl, ks * 4 + rq));
                    accz[nf] = __builtin_amdgcn_mfma_f32_16x16x32_bf16(ap, bv, accz[nf], 0, 0, 0);
                }
            }
        }
#pragma unroll
        for (int nf = 0; nf < 4; ++nf)
#pragma unroll
            for (int rr = 0; rr < 4; ++rr) {
                int qg = q0 + w * 16 + rq * 4 + rr;
                zbuf[((size_t)h * SEQ + qg) * DH + nf * 16 + cl] = f2bf(accz[nf][rr] / l_run[rr]);
            }
        __syncthreads();   // protect LDS before next half re-stages
    }
}

// ---------------------------------------------------------------------------
// Fused attn-out: per block (64 s-rows x 128 model cols), loop 16 heads:
// GEMM z_h @ W_O_h + b_O/16 -> out row 35+h; accumulate masked MLP residual
// (+prevpart), write midb (bf16) and atomicAdd per-row S1,S2 into statsM2.
// ---------------------------------------------------------------------------
__launch_bounds__(256, 2)
__global__ void attn_fused(const unsigned short* __restrict__ zbuf,
                           const unsigned short* __restrict__ WtO,
                           const float* __restrict__ bO,
                           const float* __restrict__ mlpmaskf,
                           const float* __restrict__ prevpart,
                           float* __restrict__ outp,
                           unsigned short* __restrict__ midb,
                           float* __restrict__ statsM2) {
    __shared__ unsigned short As[64 * 64];    // z tile [s][d]
    __shared__ unsigned short Bs[128 * 64];   // W_O^T tile [m][d]
    const int tid = threadIdx.x;
    const int lane = tid & 63;
    const int w = tid >> 6;          // WGM=1, WGN=4 -> wn = w
    const int cl = lane & 15, rq = lane >> 4;
    const int lrow8 = lane >> 3;
    const int scol = swz_src(lane);
    const int m0 = blockIdx.x * 64;
    const int n0 = blockIdx.y * 128;

    f32x4 macc[4][2];
#pragma unroll
    for (int mf = 0; mf < 4; ++mf)
#pragma unroll
        for (int nf = 0; nf < 2; ++nf)
#pragma unroll
            for (int rr = 0; rr < 4; ++rr) {
                int row = m0 + mf * 16 + rq * 4 + rr;
                int col = n0 + w * 32 + nf * 16 + cl;
                macc[mf][nf][rr] = prevpart[(size_t)row * DM + col];
            }

#pragma unroll 1
    for (int h = 0; h < NHEADS; ++h) {
        __syncthreads();
#pragma unroll
        for (int i = 0; i < 2; ++i) {
            int c = w * 2 + i;
            int row = c * 8 + lrow8;
            gload_lds16(zbuf + ((size_t)h * SEQ + m0 + row) * DH + scol, (char*)As + c * 1024);
        }
#pragma unroll
        for (int i = 0; i < 4; ++i) {
            int c = w * 4 + i;
            int row = c * 8 + lrow8;
            gload_lds16(WtO + ((size_t)h * DM + n0 + row) * DH + scol, (char*)Bs + c * 1024);
        }
        __syncthreads();
        f32x4 acc[4][2];
#pragma unroll
        for (int mf = 0; mf < 4; ++mf)
#pragma unroll
            for (int nf = 0; nf < 2; ++nf) acc[mf][nf] = 0.f;
#pragma unroll
        for (int ks = 0; ks < 2; ++ks) {
            bf16x8 a[4], b[2];
#pragma unroll
            for (int mf = 0; mf < 4; ++mf) {
                int ra = mf * 16 + cl;
                a[mf] = *(const bf16x8*)((const char*)As + ra * 128 + swz_off(cl, ks * 4 + rq));
            }
#pragma unroll
            for (int nf = 0; nf < 2; ++nf) {
                int rb = w * 32 + nf * 16 + cl;
                b[nf] = *(const bf16x8*)((const char*)Bs + rb * 128 + swz_off(cl, ks * 4 + rq));
            }
#pragma unroll
            for (int mf = 0; mf < 4; ++mf)
#pragma unroll
                for (int nf = 0; nf < 2; ++nf)
                    acc[mf][nf] = __builtin_amdgcn_mfma_f32_16x16x32_bf16(a[mf], b[nf], acc[mf][nf], 0, 0, 0);
        }
        float mh = mlpmaskf[PN + h];   // uniform
#pragma unroll
        for (int nf = 0; nf < 2; ++nf) {
            int col = n0 + w * 32 + nf * 16 + cl;
            float bv = bO[col] * (1.f / 16.f);
#pragma unroll
            for (int mf = 0; mf < 4; ++mf)
#pragma unroll
                for (int rr = 0; rr < 4; ++rr) {
                    int row = m0 + mf * 16 + rq * 4 + rr;
                    float v = acc[mf][nf][rr] + bv;
                    outp[(size_t)row * (OUTN * DM) + (PN + h) * DM + col] = v;
                    macc[mf][nf][rr] += mh * v;
                }
        }
    }
    // write midb + row-stats partials (this block covers cols n0..n0+127)
#pragma unroll
    for (int mf = 0; mf < 4; ++mf)
#pragma unroll
        for (int rr = 0; rr < 4; ++rr) {
            float v0 = macc[mf][0][rr], v1 = macc[mf][1][rr];
            int row = m0 + mf * 16 + rq * 4 + rr;
            int col0 = n0 + w * 32 + cl;
            midb[(size_t)row * DM + col0] = f2bf(v0);
            midb[(size_t)row * DM + col0 + 16] = f2bf(v1);
            float s1 = v0 + v1;
            float s2 = v0 * v0 + v1 * v1;
#pragma unroll
            for (int d = 1; d < 16; d <<= 1) {
                s1 += __shfl_xor(s1, d);
                s2 += __shfl_xor(s2, d);
            }
            if (cl == 0) {
                atomicAdd(&statsM2[row * 2], s1);
                atomicAdd(&statsM2[row * 2 + 1], s2);
            }
        }
}

// ---------------------------------------------------------------------------
extern "C" void kernel_launch(void* const* d_in, const int* in_sizes, int n_in,
                              void* d_out, int out_size, void* d_ws, size_t ws_size,
                              hipStream_t stream) {
    const float* resid = (const float*)d_in[0];
    const float* W_Q = (const float*)d_in[1];
    const float* b_Q = (const float*)d_in[2];
    const float* W_K = (const float*)d_in[3];
    const float* b_K = (const float*)d_in[4];
    const float* W_V = (const float*)d_in[5];
    const float* b_V = (const float*)d_in[6];
    const float* W_O = (const float*)d_in[7];
    const float* b_O = (const float*)d_in[8];
    const float* mql = (const float*)d_in[9];
    const float* mkl = (const float*)d_in[10];
    const float* mvl = (const float*)d_in[11];
    const float* mml = (const float*)d_in[12];
    const float* W_in = (const float*)d_in[13];
    const float* b_in = (const float*)d_in[14];
    const float* W_out = (const float*)d_in[15];
    const float* b_out = (const float*)d_in[16];
    float* out = (float*)d_out;
    (void)in_sizes; (void)n_in; (void)out_size; (void)ws_size;

    char* ws = (char*)d_ws;
    size_t off = 0;
    auto carve = [&](size_t bytes) -> void* {
        void* p = ws + off;
        off += (bytes + 255) & ~(size_t)255;
        return p;
    };
    unsigned short* nrm = (unsigned short*)carve((size_t)48 * SEQ * DM * 2);  // 192 MB
    float* statsQ = (float*)carve((size_t)48 * SEQ * 2 * 4);
    unsigned short* qkv = (unsigned short*)carve((size_t)48 * SEQ * DH * 2);  // q,k slices used
    unsigned short* vtb = (unsigned short*)carve((size_t)NHEADS * DH * SEQ * 2);
    unsigned short* zbuf = (unsigned short*)carve((size_t)NHEADS * SEQ * DH * 2);
    unsigned short* midb = (unsigned short*)carve((size_t)SEQ * DM * 2);
    float* statsM2 = (float*)carve((size_t)SEQ * 2 * 4);
    unsigned short* act = (unsigned short*)carve((size_t)SEQ * DMLP * 2);
    float* rot = (float*)carve((size_t)SEQ * 64 * 4);
    float* colWqkv = (float*)carve((size_t)48 * 64 * 4);
    float* colWin = (float*)carve((size_t)DMLP * 4);
    float* mlpmaskf = (float*)carve((size_t)64 * 4);
    float* biasQKV = (float*)carve((size_t)48 * 64 * 4);
    float* maskf = (float*)carve((size_t)PN * 64 * 4);
    float* prevpart = (float*)carve((size_t)SEQ * DM * 4);                    // 8 MB
    unsigned short* WtQKV = (unsigned short*)carve((size_t)48 * DH * DM * 2); // 6 MB
    unsigned short* WtO = (unsigned short*)carve((size_t)16 * DM * DH * 2);   // 2 MB
    unsigned short* WtIn = (unsigned short*)carve((size_t)DMLP * DM * 2);     // 8 MB
    unsigned short* WtOut = (unsigned short*)carve((size_t)DM * DMLP * 2);    // 8 MB

    prep_all<<<292, 256, 0, stream>>>(mql, mkl, mvl, mml, b_Q, b_K, b_V,
                                      rot, maskf, mlpmaskf, biasQKV,
                                      colWqkv, colWin, statsQ, statsM2);

    wtrans_all<<<12288, 256, 0, stream>>>(W_Q, W_K, W_V, W_O, W_in, W_out,
                                          WtQKV, WtO, WtIn, WtOut, colWqkv, colWin);

    k1_masked_norm<<<dim3(SEQ, 4), 256, 0, stream>>>(resid, maskf, out, nrm,
                                                     statsQ, prevpart);

    // QKV projection: 48 GEMMs (2048x1024x64); V written transposed to vtb
    gemm2<2, 4, 4, 1, 1><<<dim3(16, 1, 48), 256, 0, stream>>>(
        nrm, (size_t)SEQ * DM, DM,
        WtQKV, (size_t)DH * DM, DM,
        nullptr, qkv, (size_t)SEQ * DH, DH,
        statsQ, SEQ,
        colWqkv, 64,
        biasQKV, 64, 1.f,
        rot, vtb, DM);

    flash_k<<<dim3(16, 16), 256, 0, stream>>>(qkv, vtb, zbuf);

    attn_fused<<<dim3(32, 8), 256, 0, stream>>>(zbuf, WtO, b_O, mlpmaskf, prevpart,
                                                out, midb, statsM2);

    // MLP1: (2048x1024)@(1024x4096), LN fold (raw stats) + b_in + gelu -> act
    gemm2<4, 4, 2, 2, 2><<<dim3(16, 32, 1), 256, 0, stream>>>(
        midb, 0, DM,
        WtIn, 0, DM,
        nullptr, act, 0, DMLP,
        statsM2, 0,
        colWin, 0,
        b_in, 0, 1.f,
        nullptr, nullptr, DM);

    // MLP2: (2048x4096)@(4096x1024) + b_out -> d_out row 51
    gemm2<2, 4, 2, 2, 0><<<dim3(32, 8, 1), 256, 0, stream>>>(
        act, 0, DMLP,
        WtOut, 0, DMLP,
        out + 51 * DM, nullptr, 0, OUTN * DM,
        nullptr, 0, nullptr, 0,
        b_out, 0, 1.f,
        nullptr, nullptr, DMLP);
}

// Round 12
// 529.641 us; speedup vs baseline: 1.3456x; 1.2928x over previous
//
#include <hip/hip_runtime.h>
#include <stdint.h>

// ---------------------------------------------------------------------------
// TransformerBlock (masked-subnetwork block) for MI355X / gfx950.  Round 12:
//  - k1: round 8's SGPR-mask/v_fmac loop (best measured: 263 us) with the
//    stats epilogue REMOVED (576 shfl_xor/thread was co-equal with the main
//    loop -- the real cost rounds 5-11 kept paying).  k1 now only writes
//    nrm/copy/prevpart.
//  - new stats48 kernel: 1 wave per (t,s) row of nrm computes raw (S1,S2)
//    (memory-bound ~32 us); QKV epilogue finalizes as before.
//  - everything else identical to round 8.
// ---------------------------------------------------------------------------

#define SEQ 2048
#define DM 1024
#define NHEADS 16
#define DH 64
#define DMLP 4096
#define PN 35
#define TOTN 51
#define OUTN 52
#define LNEPS 1e-5f
#define L2E 1.44269504088896340736f

typedef __bf16 bf16x8 __attribute__((ext_vector_type(8)));
typedef float f32x4 __attribute__((ext_vector_type(4)));
typedef float f32x16 __attribute__((ext_vector_type(16)));
typedef unsigned short u16x8 __attribute__((ext_vector_type(8)));

static __device__ __forceinline__ unsigned short f2bf(float f) {
    unsigned int u = __builtin_bit_cast(unsigned int, f);
    u += 0x7fffu + ((u >> 16) & 1u);
    return (unsigned short)(u >> 16);
}

static __device__ __forceinline__ float bf2f(unsigned short v) {
    unsigned int u = ((unsigned int)v) << 16;
    return __builtin_bit_cast(float, u);
}

static __device__ __forceinline__ unsigned int cvt_pk_bf16(float lo, float hi) {
    unsigned int pk;
    asm("v_cvt_pk_bf16_f32 %0, %1, %2" : "=v"(pk) : "v"(lo), "v"(hi));
    return pk;
}

static __device__ __forceinline__ float gelu_tanh(float x) {
    float u = 0.7978845608028654f * x * (1.f + 0.044715f * x * x);
    float e = exp2f(u * (2.f * L2E));          // e^{2u}
    float th = 1.f - 2.f / (e + 1.f);          // tanh(u)
    return 0.5f * x * (1.f + th);
}

// async global->LDS, 16B per lane; lds dest wave-uniform base + lane*16.
static __device__ __forceinline__ void gload_lds16(const void* g, void* l) {
    __builtin_amdgcn_global_load_lds(
        (const __attribute__((address_space(1))) unsigned int*)g,
        (__attribute__((address_space(3))) unsigned int*)l, 16, 0, 0);
}

// XOR-granule swizzle: LDS[row][g] holds global[row][g ^ (row&7)], g = 16B
// granule within a 128B row.
static __device__ __forceinline__ int swz_src(int lane) {
    return ((lane & 7) ^ ((lane >> 3) & 7)) * 8;
}
static __device__ __forceinline__ int swz_off(int r, int g) {
    return ((g ^ (r & 7)) * 16);
}

// ---------------------------------------------------------------------------
// prep: rotary table, mask FLOAT table, biases, zero statsM2/colsums.
// maskf[n*64+t]: t<48 -> mask_{q,k,v}[n, t&15]>0 ? 1 : 0 (t>>4 = q/k/v);
// t==48 -> mlp mask; t>48 -> 0.  Grid 261.
// ---------------------------------------------------------------------------
__global__ void prep_all(const float* __restrict__ mq, const float* __restrict__ mk,
                         const float* __restrict__ mv, const float* __restrict__ mmlp,
                         const float* __restrict__ bQ, const float* __restrict__ bK,
                         const float* __restrict__ bV,
                         float* __restrict__ rot, float* __restrict__ maskf,
                         float* __restrict__ mlpmaskf, float* __restrict__ biasQKV,
                         float* __restrict__ colWqkv, float* __restrict__ colWin,
                         float* __restrict__ statsM2) {
    int bid = blockIdx.x, tid = threadIdx.x;
    if (bid < 256) {
        int id = bid * 256 + tid;            // 2048*32
        int s = id >> 5, j = id & 31;
        float freq = powf(10000.f, (float)j * (1.f / 32.f));
        float ang = (float)s / freq;
        rot[s * 64 + j] = sinf(ang);
        rot[s * 64 + 32 + j] = cosf(ang);
    } else if (bid == 256) {
        if (tid < PN) {
            int n = tid;
            for (int t = 0; t < 64; ++t) {
                float f = 0.f;
                if (t < 48) {
                    int ty = t >> 4, h = t & 15;
                    const float* src = (ty == 0) ? mq : (ty == 1 ? mk : mv);
                    f = (src[n * NHEADS + h] > 0.f) ? 1.f : 0.f;
                } else if (t == 48) {
                    f = (mmlp[n] > 0.f) ? 1.f : 0.f;
                }
                maskf[n * 64 + t] = f;
            }
        }
        if (tid >= 64 && tid < 112) {
            int t = tid - 64;
            int ty = t >> 4, h = t & 15;
            const float* bsrc = (ty == 0) ? bQ : (ty == 1 ? bK : bV);
            for (int d = 0; d < DH; ++d) biasQKV[t * 64 + d] = bsrc[h * DH + d];
        }
        if (tid >= 112 && tid < 176) {
            int i = tid - 112;
            mlpmaskf[i] = (i < TOTN && mmlp[i] > 0.f) ? 1.f : 0.f;
        }
    } else if (bid == 257) {
        for (int i = tid; i < SEQ * 2; i += 256) statsM2[i] = 0.f;
    } else if (bid == 258) {
        for (int i = tid; i < 3072; i += 256) colWqkv[i] = 0.f;
    } else {
        int base = (bid - 259) * 2048;
        for (int i = tid; i < 2048; i += 256) colWin[base + i] = 0.f;
    }
}

// ---------------------------------------------------------------------------
// All weight transposes in one launch.  f32 KxN row-major -> bf16 NxK
// row-major; optional column-sum accumulation.  Flat grid of 12288 blocks.
// ---------------------------------------------------------------------------
__global__ void wtrans_all(const float* __restrict__ WQ, const float* __restrict__ WK,
                           const float* __restrict__ WV, const float* __restrict__ WO,
                           const float* __restrict__ Win, const float* __restrict__ Wout,
                           unsigned short* __restrict__ WtQKV, unsigned short* __restrict__ WtO,
                           unsigned short* __restrict__ WtIn, unsigned short* __restrict__ WtOut,
                           float* __restrict__ colWqkv, float* __restrict__ colWin) {
    int bid = blockIdx.x;
    const float* src; unsigned short* dst;
    int K, N, n0, k0;
    float* cs = nullptr;
    if (bid < 3072) {                        // W_Q / W_K / W_V: each 16 z * 64 blocks
        int ty = bid >> 10;                  // 0,1,2
        int b = bid & 1023;
        int z = b >> 6, r = b & 63;
        int zeff = ty * 16 + z;
        src = ((ty == 0) ? WQ : (ty == 1 ? WK : WV)) + (size_t)z * DM * DH;
        dst = WtQKV + (size_t)zeff * DH * DM;
        K = DM; N = DH;
        n0 = (r & 1) * 32; k0 = (r >> 1) * 32;
        cs = colWqkv + zeff * 64;
    } else if (bid < 4096) {                 // W_O: 16 z * 64 blocks
        int b = bid - 3072;
        int z = b >> 6, r = b & 63;
        src = WO + (size_t)z * DH * DM;
        dst = WtO + (size_t)z * DM * DH;
        K = DH; N = DM;
        n0 = (r & 31) * 32; k0 = (r >> 5) * 32;
    } else if (bid < 8192) {                 // W_in: 128 x 32
        int b = bid - 4096;
        src = Win; dst = WtIn;
        K = DM; N = DMLP;
        n0 = (b & 127) * 32; k0 = (b >> 7) * 32;
        cs = colWin;
    } else {                                 // W_out: 32 x 128
        int b = bid - 8192;
        src = Wout; dst = WtOut;
        K = DMLP; N = DM;
        n0 = (b & 31) * 32; k0 = (b >> 5) * 32;
    }
    __shared__ float t[32][33];
    int tx = threadIdx.x & 31, ty2 = threadIdx.x >> 5;   // 32x8
#pragma unroll
    for (int r = 0; r < 4; ++r) {
        int k = ty2 + r * 8;
        t[k][tx] = src[(size_t)(k0 + k) * N + n0 + tx];
    }
    __syncthreads();
#pragma unroll
    for (int r = 0; r < 4; ++r) {
        int n = ty2 + r * 8;
        dst[(size_t)(n0 + n) * K + k0 + tx] = f2bf(t[tx][n]);
    }
    if (cs != nullptr && ty2 == 0) {
        float s = 0.f;
#pragma unroll
        for (int k = 0; k < 32; ++k) s += t[k][tx];
        atomicAdd(&cs[n0 + tx], s);
    }
}

// ---------------------------------------------------------------------------
// K1: float2 per thread, grid (SEQ, 2) x 256.  Mask row -> SGPRs via
// s_load_dwordx16; one v_fmac per (n,t); depth-2 prefetch.  Writes copy,
// packed bf16 sums, prevpart.  NO stats epilogue (stats48 does it).
// ---------------------------------------------------------------------------
__launch_bounds__(256, 3)
__global__ void k1_masked_norm(const float* __restrict__ resid,
                               const float* __restrict__ maskf,
                               float* __restrict__ outp,
                               unsigned short* __restrict__ nrm,
                               float* __restrict__ prevpart) {
    const int s = blockIdx.x;
    const int tid = threadIdx.x;
    const int col2 = blockIdx.y * 256 + tid;       // float2 index
    const float2* rp = (const float2*)(resid + (size_t)s * PN * DM) + col2;
    float2* op = (float2*)(outp + (size_t)s * OUTN * DM) + col2;
    f32x4 X0 = 0.f, X1 = 0.f, X2 = 0.f, X3 = 0.f, X4 = 0.f, X5 = 0.f,
          X6 = 0.f, X7 = 0.f, X8 = 0.f, X9 = 0.f, X10 = 0.f, X11 = 0.f;
    f32x4 Y0 = 0.f, Y1 = 0.f, Y2 = 0.f, Y3 = 0.f, Y4 = 0.f, Y5 = 0.f,
          Y6 = 0.f, Y7 = 0.f, Y8 = 0.f, Y9 = 0.f, Y10 = 0.f, Y11 = 0.f;
    float pmx = 0.f, pmy = 0.f;
    float2 v = rp[0];
    float2 vp = rp[DM / 2];
#pragma unroll 1
    for (int n = 0; n < PN; ++n) {
        f32x16 m0, m1, m2;
        float mml;
        asm volatile(
            "s_load_dwordx16 %0, %4, 0x0\n"
            "s_load_dwordx16 %1, %4, 0x40\n"
            "s_load_dwordx16 %2, %4, 0x80\n"
            "s_load_dword    %3, %4, 0xc0\n"
            "s_waitcnt lgkmcnt(0)\n"
            : "=s"(m0), "=s"(m1), "=s"(m2), "=s"(mml)
            : "s"(maskf + n * 64));
        int np = (n + 2 < PN) ? (n + 2) : (PN - 1);
        float2 vn = rp[np * (DM / 2)];
        op[n * (DM / 2)] = v;
        float vx = v.x, vy = v.y;
#define FMA4(XV, YV, MS, B) \
        XV[0] += MS[(B)] * vx;     YV[0] += MS[(B)] * vy; \
        XV[1] += MS[(B) + 1] * vx; YV[1] += MS[(B) + 1] * vy; \
        XV[2] += MS[(B) + 2] * vx; YV[2] += MS[(B) + 2] * vy; \
        XV[3] += MS[(B) + 3] * vx; YV[3] += MS[(B) + 3] * vy;
        FMA4(X0, Y0, m0, 0)  FMA4(X1, Y1, m0, 4)  FMA4(X2, Y2, m0, 8)  FMA4(X3, Y3, m0, 12)
        FMA4(X4, Y4, m1, 0)  FMA4(X5, Y5, m1, 4)  FMA4(X6, Y6, m1, 8)  FMA4(X7, Y7, m1, 12)
        FMA4(X8, Y8, m2, 0)  FMA4(X9, Y9, m2, 4)  FMA4(X10, Y10, m2, 8) FMA4(X11, Y11, m2, 12)
#undef FMA4
        pmx += mml * vx;
        pmy += mml * vy;
        v = vp;
        vp = vn;
    }
    ((float2*)prevpart)[(size_t)s * (DM / 2) + col2] = make_float2(pmx, pmy);
    // epilogue: pack + store only (no reductions)
#define ST(XV, YV, C, T) \
    ((unsigned int*)nrm)[((size_t)(T) * SEQ + s) * (DM / 2) + col2] = cvt_pk_bf16(XV[C], YV[C]);
#define ST4(XV, YV, B) ST(XV, YV, 0, B) ST(XV, YV, 1, (B) + 1) ST(XV, YV, 2, (B) + 2) ST(XV, YV, 3, (B) + 3)
    ST4(X0, Y0, 0)  ST4(X1, Y1, 4)  ST4(X2, Y2, 8)  ST4(X3, Y3, 12)
    ST4(X4, Y4, 16) ST4(X5, Y5, 20) ST4(X6, Y6, 24) ST4(X7, Y7, 28)
    ST4(X8, Y8, 32) ST4(X9, Y9, 36) ST4(X10, Y10, 40) ST4(X11, Y11, 44)
#undef ST4
#undef ST
}

// ---------------------------------------------------------------------------
// stats48: raw (S1,S2) per (t,s) row of nrm.  1 wave per row, 16 bf16/lane.
// grid 48*SEQ/4 blocks x 256.
// ---------------------------------------------------------------------------
__launch_bounds__(256, 4)
__global__ void stats48(const unsigned short* __restrict__ nrm,
                        float* __restrict__ statsQ) {
    const int row = blockIdx.x * 4 + (threadIdx.x >> 6);
    const int lane = threadIdx.x & 63;
    const unsigned short* r = nrm + (size_t)row * DM + lane * 16;
    u16x8 a = *(const u16x8*)(r);
    u16x8 b = *(const u16x8*)(r + 8);
    float s1 = 0.f, s2 = 0.f;
#pragma unroll
    for (int e = 0; e < 8; ++e) {
        float f0 = bf2f(a[e]);
        float f1 = bf2f(b[e]);
        s1 += f0 + f1;
        s2 += f0 * f0 + f1 * f1;
    }
#pragma unroll
    for (int d = 1; d < 64; d <<= 1) {
        s1 += __shfl_xor(s1, d);
        s2 += __shfl_xor(s2, d);
    }
    if (lane == 0) {
        statsQ[(size_t)row * 2] = s1;
        statsQ[(size_t)row * 2 + 1] = s2;
    }
}

// ---------------------------------------------------------------------------
// m97-style bf16 GEMM: A MxK bf16 row-major, Bt NxK bf16 row-major.
// C = A*Bt^T.  gload_lds(16B) staging, XOR-granule swizzled LDS, BK=64.
// EPI 0: f32 out + bias*scale
// EPI 1: LN-affine (RAW S1,S2) + bias + rotary(q,k) + q*0.125 -> bf16;
//        V transposed to Vt.
// EPI 2: LN-affine (RAW S1,S2) + bias + gelu -> bf16
// ---------------------------------------------------------------------------
template <int MF, int NF, int WGM, int WGN, int EPI>
__launch_bounds__(256, 2)
__global__ void gemm2(const unsigned short* __restrict__ A, size_t aZ, int lda,
                      const unsigned short* __restrict__ Bt, size_t bZ, int ldb,
                      float* __restrict__ Cf, unsigned short* __restrict__ Cb,
                      size_t cZ, int ldc,
                      const float* __restrict__ stats, size_t statsZ,
                      const float* __restrict__ colW, size_t colwZ,
                      const float* __restrict__ bias, size_t biasZ, float biasScale,
                      const float* __restrict__ rot, unsigned short* __restrict__ Vt,
                      int K) {
    constexpr int BM = WGM * 16 * MF;
    constexpr int BN = WGN * 16 * NF;
    constexpr int nA = BM / 32;
    constexpr int nB = BN / 32;
    __shared__ unsigned short As[BM * 64];
    __shared__ unsigned short Bs[BN * 64];
    const int tid = threadIdx.x;
    const int lane = tid & 63;
    const int w = tid >> 6;
    const int wm = w % WGM, wn = w / WGM;
    const int z = blockIdx.z;
    const int m0 = blockIdx.x * BM;
    const int n0 = blockIdx.y * BN;
    const int cl = lane & 15, rq = lane >> 4;

    const unsigned short* Ab = A + (size_t)z * aZ + (size_t)m0 * lda;
    const unsigned short* Bb = Bt + (size_t)z * bZ + (size_t)n0 * ldb;
    const int lrow8 = lane >> 3;
    const int scol = swz_src(lane);

    f32x4 acc[MF][NF];
#pragma unroll
    for (int mf = 0; mf < MF; ++mf)
#pragma unroll
        for (int nf = 0; nf < NF; ++nf) acc[mf][nf] = 0.f;

    for (int k0 = 0; k0 < K; k0 += 64) {
        __syncthreads();
#pragma unroll
        for (int i = 0; i < nA; ++i) {
            int c = w * nA + i;
            int row = c * 8 + lrow8;
            gload_lds16(Ab + (size_t)row * lda + k0 + scol, (char*)As + c * 1024);
        }
#pragma unroll
        for (int i = 0; i < nB; ++i) {
            int c = w * nB + i;
            int row = c * 8 + lrow8;
            gload_lds16(Bb + (size_t)row * ldb + k0 + scol, (char*)Bs + c * 1024);
        }
        __syncthreads();
#pragma unroll
        for (int ks = 0; ks < 2; ++ks) {
            bf16x8 a[MF], b[NF];
#pragma unroll
            for (int mf = 0; mf < MF; ++mf) {
                int ra = (wm * MF + mf) * 16 + cl;
                a[mf] = *(const bf16x8*)((const char*)As + ra * 128 + swz_off(cl, ks * 4 + rq));
            }
#pragma unroll
            for (int nf = 0; nf < NF; ++nf) {
                int rb = (wn * NF + nf) * 16 + cl;
                b[nf] = *(const bf16x8*)((const char*)Bs + rb * 128 + swz_off(cl, ks * 4 + rq));
            }
#pragma unroll
            for (int mf = 0; mf < MF; ++mf)
#pragma unroll
                for (int nf = 0; nf < NF; ++nf)
                    acc[mf][nf] = __builtin_amdgcn_mfma_f32_16x16x32_bf16(a[mf], b[nf], acc[mf][nf], 0, 0, 0);
        }
    }

    if constexpr (EPI == 0) {
        float* Cz = Cf + (size_t)z * cZ;
        const float* bz = bias + (size_t)z * biasZ;
#pragma unroll
        for (int mf = 0; mf < MF; ++mf)
#pragma unroll
            for (int nf = 0; nf < NF; ++nf) {
                int col = n0 + wn * (16 * NF) + nf * 16 + cl;
                float bv = bz[col] * biasScale;
#pragma unroll
                for (int rr = 0; rr < 4; ++rr) {
                    int row = m0 + wm * (16 * MF) + mf * 16 + rq * 4 + rr;
                    Cz[(size_t)row * ldc + col] = acc[mf][nf][rr] + bv;
                }
            }
    } else if constexpr (EPI == 1) {
        const int t = z >> 4;                      // 0=q 1=k 2=v
        const int h = z & 15;
        const float qs = (t == 0) ? 0.125f : 1.f;
        float vals[MF][NF][4];
        float meanv[MF][4], invv[MF][4];
#pragma unroll
        for (int mf = 0; mf < MF; ++mf)
#pragma unroll
            for (int rr = 0; rr < 4; ++rr) {
                int row = m0 + wm * (16 * MF) + mf * 16 + rq * 4 + rr;
                const float* st = stats + ((size_t)z * statsZ + row) * 2;
                float S1 = st[0], S2 = st[1];
                float mean = S1 * (1.f / DM);
                meanv[mf][rr] = mean;
                invv[mf][rr] = rsqrtf(S2 * (1.f / DM) - mean * mean + LNEPS);
            }
#pragma unroll
        for (int nf = 0; nf < NF; ++nf) {
            int col = n0 + wn * (16 * NF) + nf * 16 + cl;
            float cw = colW[(size_t)z * colwZ + col];
            float bv = bias[(size_t)z * biasZ + col];
#pragma unroll
            for (int mf = 0; mf < MF; ++mf)
#pragma unroll
                for (int rr = 0; rr < 4; ++rr)
                    vals[mf][nf][rr] = (acc[mf][nf][rr] - meanv[mf][rr] * cw) * invv[mf][rr] + bv;
        }
        if (t < 2) {   // rotary on q,k  (WGN==1, n0==0, NF==4 -> pairs (nf, nf+2))
#pragma unroll
            for (int nf = 0; nf < NF / 2; ++nf) {
                int j = nf * 16 + cl;
#pragma unroll
                for (int mf = 0; mf < MF; ++mf)
#pragma unroll
                    for (int rr = 0; rr < 4; ++rr) {
                        int row = m0 + wm * (16 * MF) + mf * 16 + rq * 4 + rr;
                        float sn = rot[row * 64 + j];
                        float cs = rot[row * 64 + 32 + j];
                        float lo = vals[mf][nf][rr], hi = vals[mf][nf + 2][rr];
                        vals[mf][nf][rr] = lo * cs - hi * sn;
                        vals[mf][nf + 2][rr] = hi * cs + lo * sn;
                    }
            }
        }
        if (t == 2) {
#pragma unroll
            for (int mf = 0; mf < MF; ++mf)
#pragma unroll
                for (int nf = 0; nf < NF; ++nf) {
                    int col = nf * 16 + cl;   // d
                    int row0 = m0 + wm * (16 * MF) + mf * 16 + rq * 4;
                    ushort4 pk;
                    pk.x = f2bf(vals[mf][nf][0]);
                    pk.y = f2bf(vals[mf][nf][1]);
                    pk.z = f2bf(vals[mf][nf][2]);
                    pk.w = f2bf(vals[mf][nf][3]);
                    *(ushort4*)&Vt[((size_t)h * DH + col) * SEQ + row0] = pk;
                }
        } else {
            unsigned short* Cz = Cb + (size_t)z * cZ;
#pragma unroll
            for (int mf = 0; mf < MF; ++mf)
#pragma unroll
                for (int nf = 0; nf < NF; ++nf) {
                    int col = n0 + wn * (16 * NF) + nf * 16 + cl;
#pragma unroll
                    for (int rr = 0; rr < 4; ++rr) {
                        int row = m0 + wm * (16 * MF) + mf * 16 + rq * 4 + rr;
                        Cz[(size_t)row * ldc + col] = f2bf(vals[mf][nf][rr] * qs);
                    }
                }
        }
    } else {  // EPI == 2 : LN-affine from RAW (S1,S2) + bias + gelu -> bf16
        unsigned short* Cz = Cb;
#pragma unroll
        for (int mf = 0; mf < MF; ++mf)
#pragma unroll
            for (int rr = 0; rr < 4; ++rr) {
                int row = m0 + wm * (16 * MF) + mf * 16 + rq * 4 + rr;
                float S1 = stats[(size_t)row * 2];
                float S2 = stats[(size_t)row * 2 + 1];
                float mean = S1 * (1.f / DM);
                float inv = rsqrtf(S2 * (1.f / DM) - mean * mean + LNEPS);
#pragma unroll
                for (int nf = 0; nf < NF; ++nf) {
                    int col = n0 + wn * (16 * NF) + nf * 16 + cl;
                    float x = (acc[mf][nf][rr] - mean * colW[col]) * inv + bias[col];
                    Cz[(size_t)row * ldc + col] = f2bf(gelu_tanh(x));
                }
            }
    }
}

// ---------------------------------------------------------------------------
// Flash attention: balanced pairs {p, 31-p} of 64-row q-tiles, 16 heads.
// ---------------------------------------------------------------------------
__launch_bounds__(256, 2)
__global__ void flash_k(const unsigned short* __restrict__ qkv,
                        const unsigned short* __restrict__ vt,
                        unsigned short* __restrict__ zbuf) {
    const int p = blockIdx.x, h = blockIdx.y;
    const int tid = threadIdx.x, lane = tid & 63, w = tid >> 6;
    const int cl = lane & 15, rq = lane >> 4;
    const int lrow8 = lane >> 3;
    const int scol = swz_src(lane);
    const unsigned short* qb = qkv + ((size_t)h * SEQ) * DH;
    const unsigned short* kb = qkv + ((size_t)(16 + h) * SEQ) * DH;
    const unsigned short* vtb = vt + (size_t)h * DH * SEQ;

    __shared__ unsigned short Ks[64 * 64];   // [k][d] swizzled
    __shared__ unsigned short Vs[64 * 64];   // [d][k] swizzled
    __shared__ unsigned short Ps[64][72];    // padded, scalar writes

#pragma unroll 1
    for (int half = 0; half < 2; ++half) {
        const int qi = half ? (31 - p) : p;
        const int q0 = qi * 64;

        bf16x8 aq[2];
        {
            int qrow = q0 + w * 16 + cl;
            const unsigned short* qp = qb + (size_t)qrow * DH + rq * 8;
            aq[0] = *(const bf16x8*)(qp);
            aq[1] = *(const bf16x8*)(qp + 32);
        }
        float m_run[4] = {-3e38f, -3e38f, -3e38f, -3e38f};
        float l_run[4] = {0.f, 0.f, 0.f, 0.f};
        f32x4 accz[4];
#pragma unroll
        for (int nf = 0; nf < 4; ++nf) accz[nf] = 0.f;

#pragma unroll 1
        for (int j = 0; j <= qi; ++j) {
            __syncthreads();
#pragma unroll
            for (int i = 0; i < 2; ++i) {
                int c = w * 2 + i;
                int row = c * 8 + lrow8;
                gload_lds16(kb + (size_t)(j * 64 + row) * DH + scol, (char*)Ks + c * 1024);
                gload_lds16(vtb + (size_t)row * SEQ + j * 64 + scol, (char*)Vs + c * 1024);
            }
            __syncthreads();

            f32x4 sfr[4];
#pragma unroll
            for (int nf = 0; nf < 4; ++nf) sfr[nf] = 0.f;
#pragma unroll
            for (int df = 0; df < 2; ++df)
#pragma unroll
                for (int nf = 0; nf < 4; ++nf) {
                    int rb = nf * 16 + cl;
                    bf16x8 b = *(const bf16x8*)((const char*)Ks + rb * 128 + swz_off(cl, df * 4 + rq));
                    sfr[nf] = __builtin_amdgcn_mfma_f32_16x16x32_bf16(aq[df], b, sfr[nf], 0, 0, 0);
                }
            if (j == qi) {
#pragma unroll
                for (int nf = 0; nf < 4; ++nf)
#pragma unroll
                    for (int rr = 0; rr < 4; ++rr) {
                        int qg = q0 + w * 16 + rq * 4 + rr;
                        int kg = j * 64 + nf * 16 + cl;
                        if (kg > qg) sfr[nf][rr] = -1e5f;
                    }
            }
            float mnew[4], corr[4], psum[4];
#pragma unroll
            for (int rr = 0; rr < 4; ++rr) {
                float t0 = fmaxf(fmaxf(sfr[0][rr], sfr[1][rr]), fmaxf(sfr[2][rr], sfr[3][rr]));
                t0 = fmaxf(t0, __shfl_xor(t0, 1));
                t0 = fmaxf(t0, __shfl_xor(t0, 2));
                t0 = fmaxf(t0, __shfl_xor(t0, 4));
                t0 = fmaxf(t0, __shfl_xor(t0, 8));
                mnew[rr] = fmaxf(m_run[rr], t0);
                corr[rr] = exp2f((m_run[rr] - mnew[rr]) * L2E);
                psum[rr] = 0.f;
            }
#pragma unroll
            for (int nf = 0; nf < 4; ++nf)
#pragma unroll
                for (int rr = 0; rr < 4; ++rr) {
                    float pv = exp2f((sfr[nf][rr] - mnew[rr]) * L2E);
                    sfr[nf][rr] = pv;
                    psum[rr] += pv;
                }
#pragma unroll
            for (int rr = 0; rr < 4; ++rr) {
                float ps = psum[rr];
                ps += __shfl_xor(ps, 1);
                ps += __shfl_xor(ps, 2);
                ps += __shfl_xor(ps, 4);
                ps += __shfl_xor(ps, 8);
                l_run[rr] = l_run[rr] * corr[rr] + ps;
                m_run[rr] = mnew[rr];
            }
#pragma unroll
            for (int nf = 0; nf < 4; ++nf)
#pragma unroll
                for (int rr = 0; rr < 4; ++rr) accz[nf][rr] *= corr[rr];

#pragma unroll
            for (int nf = 0; nf < 4; ++nf)
#pragma unroll
                for (int rr = 0; rr < 4; ++rr)
                    Ps[w * 16 + rq * 4 + rr][nf * 16 + cl] = f2bf(sfr[nf][rr]);
#pragma unroll
            for (int ks = 0; ks < 2; ++ks) {
                bf16x8 ap = *(const bf16x8*)&Ps[w * 16 + cl][ks * 32 + rq * 8];
#pragma unroll
                for (int nf = 0; nf < 4; ++nf) {
                    int rb = nf * 16 + cl;
                    bf16x8 bv = *(const bf16x8*)((const char*)Vs + rb * 128 + swz_off(cl, ks * 4 + rq));
                    accz[nf] = __builtin_amdgcn_mfma_f32_16x16x32_bf16(ap, bv, accz[nf], 0, 0, 0);
                }
            }
        }
#pragma unroll
        for (int nf = 0; nf < 4; ++nf)
#pragma unroll
            for (int rr = 0; rr < 4; ++rr) {
                int qg = q0 + w * 16 + rq * 4 + rr;
                zbuf[((size_t)h * SEQ + qg) * DH + nf * 16 + cl] = f2bf(accz[nf][rr] / l_run[rr]);
            }
        __syncthreads();   // protect LDS before next half re-stages
    }
}

// ---------------------------------------------------------------------------
// Fused attn-out: per block (64 s-rows x 128 model cols), loop 16 heads:
// GEMM z_h @ W_O_h + b_O/16 -> out row 35+h; accumulate masked MLP residual
// (+prevpart), write midb (bf16) and atomicAdd per-row S1,S2 into statsM2.
// ---------------------------------------------------------------------------
__launch_bounds__(256, 2)
__global__ void attn_fused(const unsigned short* __restrict__ zbuf,
                           const unsigned short* __restrict__ WtO,
                           const float* __restrict__ bO,
                           const float* __restrict__ mlpmaskf,
                           const float* __restrict__ prevpart,
                           float* __restrict__ outp,
                           unsigned short* __restrict__ midb,
                           float* __restrict__ statsM2) {
    __shared__ unsigned short As[64 * 64];    // z tile [s][d]
    __shared__ unsigned short Bs[128 * 64];   // W_O^T tile [m][d]
    const int tid = threadIdx.x;
    const int lane = tid & 63;
    const int w = tid >> 6;          // WGM=1, WGN=4 -> wn = w
    const int cl = lane & 15, rq = lane >> 4;
    const int lrow8 = lane >> 3;
    const int scol = swz_src(lane);
    const int m0 = blockIdx.x * 64;
    const int n0 = blockIdx.y * 128;

    f32x4 macc[4][2];
#pragma unroll
    for (int mf = 0; mf < 4; ++mf)
#pragma unroll
        for (int nf = 0; nf < 2; ++nf)
#pragma unroll
            for (int rr = 0; rr < 4; ++rr) {
                int row = m0 + mf * 16 + rq * 4 + rr;
                int col = n0 + w * 32 + nf * 16 + cl;
                macc[mf][nf][rr] = prevpart[(size_t)row * DM + col];
            }

#pragma unroll 1
    for (int h = 0; h < NHEADS; ++h) {
        __syncthreads();
#pragma unroll
        for (int i = 0; i < 2; ++i) {
            int c = w * 2 + i;
            int row = c * 8 + lrow8;
            gload_lds16(zbuf + ((size_t)h * SEQ + m0 + row) * DH + scol, (char*)As + c * 1024);
        }
#pragma unroll
        for (int i = 0; i < 4; ++i) {
            int c = w * 4 + i;
            int row = c * 8 + lrow8;
            gload_lds16(WtO + ((size_t)h * DM + n0 + row) * DH + scol, (char*)Bs + c * 1024);
        }
        __syncthreads();
        f32x4 acc[4][2];
#pragma unroll
        for (int mf = 0; mf < 4; ++mf)
#pragma unroll
            for (int nf = 0; nf < 2; ++nf) acc[mf][nf] = 0.f;
#pragma unroll
        for (int ks = 0; ks < 2; ++ks) {
            bf16x8 a[4], b[2];
#pragma unroll
            for (int mf = 0; mf < 4; ++mf) {
                int ra = mf * 16 + cl;
                a[mf] = *(const bf16x8*)((const char*)As + ra * 128 + swz_off(cl, ks * 4 + rq));
            }
#pragma unroll
            for (int nf = 0; nf < 2; ++nf) {
                int rb = w * 32 + nf * 16 + cl;
                b[nf] = *(const bf16x8*)((const char*)Bs + rb * 128 + swz_off(cl, ks * 4 + rq));
            }
#pragma unroll
            for (int mf = 0; mf < 4; ++mf)
#pragma unroll
                for (int nf = 0; nf < 2; ++nf)
                    acc[mf][nf] = __builtin_amdgcn_mfma_f32_16x16x32_bf16(a[mf], b[nf], acc[mf][nf], 0, 0, 0);
        }
        float mh = mlpmaskf[PN + h];   // uniform
#pragma unroll
        for (int nf = 0; nf < 2; ++nf) {
            int col = n0 + w * 32 + nf * 16 + cl;
            float bv = bO[col] * (1.f / 16.f);
#pragma unroll
            for (int mf = 0; mf < 4; ++mf)
#pragma unroll
                for (int rr = 0; rr < 4; ++rr) {
                    int row = m0 + mf * 16 + rq * 4 + rr;
                    float v = acc[mf][nf][rr] + bv;
                    outp[(size_t)row * (OUTN * DM) + (PN + h) * DM + col] = v;
                    macc[mf][nf][rr] += mh * v;
                }
        }
    }
    // write midb + row-stats partials (this block covers cols n0..n0+127)
#pragma unroll
    for (int mf = 0; mf < 4; ++mf)
#pragma unroll
        for (int rr = 0; rr < 4; ++rr) {
            float v0 = macc[mf][0][rr], v1 = macc[mf][1][rr];
            int row = m0 + mf * 16 + rq * 4 + rr;
            int col0 = n0 + w * 32 + cl;
            midb[(size_t)row * DM + col0] = f2bf(v0);
            midb[(size_t)row * DM + col0 + 16] = f2bf(v1);
            float s1 = v0 + v1;
            float s2 = v0 * v0 + v1 * v1;
#pragma unroll
            for (int d = 1; d < 16; d <<= 1) {
                s1 += __shfl_xor(s1, d);
                s2 += __shfl_xor(s2, d);
            }
            if (cl == 0) {
                atomicAdd(&statsM2[row * 2], s1);
                atomicAdd(&statsM2[row * 2 + 1], s2);
            }
        }
}

// ---------------------------------------------------------------------------
extern "C" void kernel_launch(void* const* d_in, const int* in_sizes, int n_in,
                              void* d_out, int out_size, void* d_ws, size_t ws_size,
                              hipStream_t stream) {
    const float* resid = (const float*)d_in[0];
    const float* W_Q = (const float*)d_in[1];
    const float* b_Q = (const float*)d_in[2];
    const float* W_K = (const float*)d_in[3];
    const float* b_K = (const float*)d_in[4];
    const float* W_V = (const float*)d_in[5];
    const float* b_V = (const float*)d_in[6];
    const float* W_O = (const float*)d_in[7];
    const float* b_O = (const float*)d_in[8];
    const float* mql = (const float*)d_in[9];
    const float* mkl = (const float*)d_in[10];
    const float* mvl = (const float*)d_in[11];
    const float* mml = (const float*)d_in[12];
    const float* W_in = (const float*)d_in[13];
    const float* b_in = (const float*)d_in[14];
    const float* W_out = (const float*)d_in[15];
    const float* b_out = (const float*)d_in[16];
    float* out = (float*)d_out;
    (void)in_sizes; (void)n_in; (void)out_size; (void)ws_size;

    char* ws = (char*)d_ws;
    size_t off = 0;
    auto carve = [&](size_t bytes) -> void* {
        void* p = ws + off;
        off += (bytes + 255) & ~(size_t)255;
        return p;
    };
    unsigned short* nrm = (unsigned short*)carve((size_t)48 * SEQ * DM * 2);  // 192 MB
    float* statsQ = (float*)carve((size_t)48 * SEQ * 2 * 4);
    unsigned short* qkv = (unsigned short*)carve((size_t)48 * SEQ * DH * 2);  // q,k slices used
    unsigned short* vtb = (unsigned short*)carve((size_t)NHEADS * DH * SEQ * 2);
    unsigned short* zbuf = (unsigned short*)carve((size_t)NHEADS * SEQ * DH * 2);
    unsigned short* midb = (unsigned short*)carve((size_t)SEQ * DM * 2);
    float* statsM2 = (float*)carve((size_t)SEQ * 2 * 4);
    unsigned short* act = (unsigned short*)carve((size_t)SEQ * DMLP * 2);
    float* rot = (float*)carve((size_t)SEQ * 64 * 4);
    float* colWqkv = (float*)carve((size_t)48 * 64 * 4);
    float* colWin = (float*)carve((size_t)DMLP * 4);
    float* mlpmaskf = (float*)carve((size_t)64 * 4);
    float* biasQKV = (float*)carve((size_t)48 * 64 * 4);
    float* maskf = (float*)carve((size_t)PN * 64 * 4);
    float* prevpart = (float*)carve((size_t)SEQ * DM * 4);                    // 8 MB
    unsigned short* WtQKV = (unsigned short*)carve((size_t)48 * DH * DM * 2); // 6 MB
    unsigned short* WtO = (unsigned short*)carve((size_t)16 * DM * DH * 2);   // 2 MB
    unsigned short* WtIn = (unsigned short*)carve((size_t)DMLP * DM * 2);     // 8 MB
    unsigned short* WtOut = (unsigned short*)carve((size_t)DM * DMLP * 2);    // 8 MB

    prep_all<<<261, 256, 0, stream>>>(mql, mkl, mvl, mml, b_Q, b_K, b_V,
                                      rot, maskf, mlpmaskf, biasQKV,
                                      colWqkv, colWin, statsM2);

    wtrans_all<<<12288, 256, 0, stream>>>(W_Q, W_K, W_V, W_O, W_in, W_out,
                                          WtQKV, WtO, WtIn, WtOut, colWqkv, colWin);

    k1_masked_norm<<<dim3(SEQ, 2), 256, 0, stream>>>(resid, maskf, out, nrm, prevpart);

    stats48<<<48 * SEQ / 4, 256, 0, stream>>>(nrm, statsQ);

    // QKV projection: 48 GEMMs (2048x1024x64); V written transposed to vtb
    gemm2<2, 4, 4, 1, 1><<<dim3(16, 1, 48), 256, 0, stream>>>(
        nrm, (size_t)SEQ * DM, DM,
        WtQKV, (size_t)DH * DM, DM,
        nullptr, qkv, (size_t)SEQ * DH, DH,
        statsQ, SEQ,
        colWqkv, 64,
        biasQKV, 64, 1.f,
        rot, vtb, DM);

    flash_k<<<dim3(16, 16), 256, 0, stream>>>(qkv, vtb, zbuf);

    attn_fused<<<dim3(32, 8), 256, 0, stream>>>(zbuf, WtO, b_O, mlpmaskf, prevpart,
                                                out, midb, statsM2);

    // MLP1: (2048x1024)@(1024x4096), LN fold (raw stats) + b_in + gelu -> act
    gemm2<4, 4, 2, 2, 2><<<dim3(16, 32, 1), 256, 0, stream>>>(
        midb, 0, DM,
        WtIn, 0, DM,
        nullptr, act, 0, DMLP,
        statsM2, 0,
        colWin, 0,
        b_in, 0, 1.f,
        nullptr, nullptr, DM);

    // MLP2: (2048x4096)@(4096x1024) + b_out -> d_out row 51
    gemm2<2, 4, 2, 2, 0><<<dim3(32, 8, 1), 256, 0, stream>>>(
        act, 0, DMLP,
        WtOut, 0, DMLP,
        out + 51 * DM, nullptr, 0, OUTN * DM,
        nullptr, 0, nullptr, 0,
        b_out, 0, 1.f,
        nullptr, nullptr, DMLP);
}